// Round 18
// baseline (332.437 us; speedup 1.0000x reference)
//
#include <hip/hip_runtime.h>

typedef __bf16 bf16_t;
typedef __bf16 bf16x8 __attribute__((ext_vector_type(8)));
typedef __bf16 bf16x4 __attribute__((ext_vector_type(4)));
typedef float f32x4 __attribute__((ext_vector_type(4)));

typedef __attribute__((address_space(1))) const unsigned int as1_u32;
typedef __attribute__((address_space(3))) unsigned int as3_u32;

#define MFMA16(a, b, c) __builtin_amdgcn_mfma_f32_16x16x32_bf16((a), (b), (c), 0, 0, 0)
#define GLD16(src, dst) __builtin_amdgcn_global_load_lds((as1_u32*)(src), (as3_u32*)(dst), 16, 0, 0)

#define BB 4
#define TT 2048
#define DD 512
#define HH 8
#define HS 64
#define BT (BB * TT) /* 8192 */

// ---------------- fused coalesced weight packing (32x32 LDS tile transpose) ----------------
__global__ __launch_bounds__(256) void pack_fused(const float* __restrict__ Wq, const float* __restrict__ Wk,
                                                  const float* __restrict__ Wv, const float* __restrict__ Wp,
                                                  const float* __restrict__ W1, const float* __restrict__ W2,
                                                  bf16_t* __restrict__ Wqkv, bf16_t* __restrict__ Wpt,
                                                  bf16_t* __restrict__ W1t, bf16_t* __restrict__ W2t) {
    __shared__ float tile[32][33];
    int bx = blockIdx.x;
    const float* src;
    bf16_t* dst;
    int sStride, dStride, tk, tn;
    if (bx < 768) {
        int hs_t = bx & 1, d_t = (bx >> 1) & 15, h = (bx >> 5) & 7, which = bx >> 8;
        const float* W = (which == 0) ? Wq : (which == 1) ? Wk : Wv;
        src = W + (size_t)h * DD * HS;
        dst = Wqkv + (size_t)(which * 512 + h * 64) * DD;
        sStride = HS; dStride = DD; tk = d_t; tn = hs_t;
    } else if (bx < 1024) {
        int r = bx - 768;
        src = Wp; dst = Wpt; sStride = 512; dStride = 512; tn = r & 15; tk = r >> 4;
    } else if (bx < 2048) {
        int r = bx - 1024;
        src = W1; dst = W1t; sStride = 2048; dStride = 512; tn = r & 63; tk = r >> 6;
    } else {
        int r = bx - 2048;
        src = W2; dst = W2t; sStride = 512; dStride = 2048; tn = r & 15; tk = r >> 4;
    }
    int tx = threadIdx.x & 31, ty = threadIdx.x >> 5;
#pragma unroll
    for (int i = 0; i < 4; ++i)
        tile[ty + i * 8][tx] = src[(size_t)(tk * 32 + ty + i * 8) * sStride + tn * 32 + tx];
    __syncthreads();
#pragma unroll
    for (int i = 0; i < 4; ++i)
        dst[(size_t)(tn * 32 + ty + i * 8) * dStride + tk * 32 + tx] = (bf16_t)tile[tx][ty + i * 8];
}

// ---------------- layernorm: fp32 row -> bf16 row ----------------
__global__ __launch_bounds__(128) void ln_kernel(const float* __restrict__ in, const float* __restrict__ g,
                                                 const float* __restrict__ be, bf16_t* __restrict__ out) {
    int row = blockIdx.x, tid = threadIdx.x;
    float4 v = ((const float4*)(in + (size_t)row * DD))[tid];
    float s = v.x + v.y + v.z + v.w;
    float sq = v.x * v.x + v.y * v.y + v.z * v.z + v.w * v.w;
#pragma unroll
    for (int d = 32; d; d >>= 1) {
        s += __shfl_down(s, d, 64);
        sq += __shfl_down(sq, d, 64);
    }
    __shared__ float red[4];
    if ((tid & 63) == 0) { red[(tid >> 6) * 2] = s; red[(tid >> 6) * 2 + 1] = sq; }
    __syncthreads();
    s = red[0] + red[2];
    sq = red[1] + red[3];
    float mu = s * (1.0f / DD);
    float var = sq * (1.0f / DD) - mu * mu;
    float rstd = rsqrtf(var + 1e-5f);
    float4 gv = ((const float4*)g)[tid];
    float4 bv = ((const float4*)be)[tid];
    bf16x4 o;
    o[0] = (bf16_t)((v.x - mu) * rstd * gv.x + bv.x);
    o[1] = (bf16_t)((v.y - mu) * rstd * gv.y + bv.y);
    o[2] = (bf16_t)((v.z - mu) * rstd * gv.z + bv.z);
    o[3] = (bf16_t)((v.w - mu) * rstd * gv.w + bv.w);
    *(bf16x4*)(out + (size_t)row * DD + tid * 4) = o;
}

// ---------------- 128xBN bf16 GEMM, 2-phase double-buffered, BK=32 or 64, XCD-chunked ----------------
// EPI 0: QKV scatter. EPI 1: +bias+resid fp32. EPI 2: +bias ReLU bf16.
template <int EPI, int BN, int BK>
__global__ __launch_bounds__(256) void gemm_bt(const bf16_t* __restrict__ A, const bf16_t* __restrict__ Bt,
                                               int N, int K, const float* __restrict__ bias,
                                               const float* __restrict__ resid, void* __restrict__ outp) {
    __shared__ __attribute__((aligned(16))) bf16_t As[2][128][BK];
    __shared__ __attribute__((aligned(16))) bf16_t Bs[2][BN][BK];
    constexpr int WM = (BN == 128) ? 64 : 32;
    constexpr int AI = WM / 16;
    int lin = blockIdx.y * 64 + blockIdx.x;
    int total = gridDim.y * 64;
    int lin2 = (lin & 7) * (total >> 3) + (lin >> 3);
    int Nb = gridDim.y;
    int m0 = (lin2 / Nb) * 128, n0 = (lin2 % Nb) * BN;
    int tid = threadIdx.x, lane = tid & 63, w = tid >> 6;
    int wr = (BN == 128) ? (w >> 1) : w;
    int wc = (BN == 128) ? (w & 1) : 0;
    int r15 = lane & 15, g = lane >> 4;
    int l4 = lane & 3, lr = lane >> 2;
    int l8 = lane & 7, lr8 = lane >> 3;
    int src32 = (l4 ^ ((lane >> 3) & 3)) * 8;
    int src64 = ((l8 * 16) ^ (lr8 << 4)) >> 1;

    auto stage = [&](int it, int buf) {
        if constexpr (BK == 32) {
            const bf16_t* Ab = A + (size_t)(m0 + w * 32 + lr) * K + it * 32 + src32;
            GLD16(Ab, &As[buf][w * 32][0]);
            GLD16(Ab + (size_t)16 * K, &As[buf][w * 32 + 16][0]);
            if constexpr (BN == 128) {
                const bf16_t* Bb = Bt + (size_t)(n0 + w * 32 + lr) * K + it * 32 + src32;
                GLD16(Bb, &Bs[buf][w * 32][0]);
                GLD16(Bb + (size_t)16 * K, &Bs[buf][w * 32 + 16][0]);
            } else {
                const bf16_t* Bb = Bt + (size_t)(n0 + w * 16 + lr) * K + it * 32 + src32;
                GLD16(Bb, &Bs[buf][w * 16][0]);
            }
        } else {
#pragma unroll
            for (int i = 0; i < 4; ++i)
                GLD16(A + (size_t)(m0 + w * 32 + i * 8 + lr8) * K + it * 64 + src64,
                      &As[buf][w * 32 + i * 8][0]);
            if constexpr (BN == 128) {
#pragma unroll
                for (int i = 0; i < 4; ++i)
                    GLD16(Bt + (size_t)(n0 + w * 32 + i * 8 + lr8) * K + it * 64 + src64,
                          &Bs[buf][w * 32 + i * 8][0]);
            } else {
#pragma unroll
                for (int i = 0; i < 2; ++i)
                    GLD16(Bt + (size_t)(n0 + w * 16 + i * 8 + lr8) * K + it * 64 + src64,
                          &Bs[buf][w * 16 + i * 8][0]);
            }
        }
    };

    f32x4 acc[AI][4] = {};
    stage(0, 0);
    asm volatile("s_waitcnt vmcnt(0)\n\ts_barrier" ::: "memory");
    __builtin_amdgcn_sched_barrier(0);
    constexpr int LOGBK = (BK == 32) ? 5 : 6;
    int nit = K >> LOGBK;
    for (int it = 0; it < nit; ++it) {
        int cur = it & 1;
        if (it + 1 < nit) stage(it + 1, cur ^ 1);
        if constexpr (BK == 32) {
            int bo = (g ^ ((r15 >> 1) & 3)) * 16;
            bf16x8 a[AI], bfr[4];
#pragma unroll
            for (int i = 0; i < AI; ++i)
                a[i] = *(const bf16x8*)((const char*)&As[cur][0][0] + (wr * WM + i * 16 + r15) * 64 + bo);
#pragma unroll
            for (int j = 0; j < 4; ++j)
                bfr[j] = *(const bf16x8*)((const char*)&Bs[cur][0][0] + (wc * 64 + j * 16 + r15) * 64 + bo);
#pragma unroll
            for (int i = 0; i < AI; ++i)
#pragma unroll
                for (int j = 0; j < 4; ++j) acc[i][j] = MFMA16(bfr[j], a[i], acc[i][j]);
        } else {
#pragma unroll
            for (int kk = 0; kk < 2; ++kk) {
                int bo = (kk * 64 + g * 16) ^ ((r15 & 7) << 4);
                bf16x8 a[AI], bfr[4];
#pragma unroll
                for (int i = 0; i < AI; ++i)
                    a[i] = *(const bf16x8*)((const char*)&As[cur][0][0] + (wr * WM + i * 16 + r15) * 128 + bo);
#pragma unroll
                for (int j = 0; j < 4; ++j)
                    bfr[j] = *(const bf16x8*)((const char*)&Bs[cur][0][0] + (wc * 64 + j * 16 + r15) * 128 + bo);
#pragma unroll
                for (int i = 0; i < AI; ++i)
#pragma unroll
                    for (int j = 0; j < 4; ++j) acc[i][j] = MFMA16(bfr[j], a[i], acc[i][j]);
            }
        }
        if (it + 1 < nit) {
            asm volatile("s_waitcnt vmcnt(0)\n\ts_barrier" ::: "memory");
            __builtin_amdgcn_sched_barrier(0);
        }
    }
#pragma unroll
    for (int i = 0; i < AI; ++i)
#pragma unroll
        for (int j = 0; j < 4; ++j) {
            int row = m0 + wr * WM + i * 16 + r15;
            int col0 = n0 + wc * 64 + j * 16 + g * 4;
            f32x4 v4 = acc[i][j];
            if constexpr (EPI == 0) {
                bf16_t* o = (bf16_t*)outp;
                int b_ = row >> 11, t_ = row & 2047;
                int which = col0 >> 9, r9 = col0 & 511, h_ = r9 >> 6, hs0 = r9 & 63;
                if (which < 2) {
                    size_t dst = (size_t)which * 4194304 + (((size_t)(b_ * HH + h_)) * TT + t_) * HS + hs0;
                    bf16x4 ov = {(bf16_t)v4[0], (bf16_t)v4[1], (bf16_t)v4[2], (bf16_t)v4[3]};
                    *(bf16x4*)(o + dst) = ov;
                } else {
                    size_t dst = 8388608 + (((size_t)(b_ * HH + h_)) * HS + hs0) * TT + t_;
#pragma unroll
                    for (int r = 0; r < 4; ++r) o[dst + (size_t)r * TT] = (bf16_t)v4[r];
                }
            } else if constexpr (EPI == 1) {
                float* o = (float*)outp;
                size_t off = (size_t)row * N + col0;
                f32x4 bv = *(const f32x4*)(bias + col0);
                f32x4 rv = *(const f32x4*)(resid + off);
                *(f32x4*)(o + off) = v4 + bv + rv;
            } else {
                bf16_t* o = (bf16_t*)outp;
                f32x4 bv = *(const f32x4*)(bias + col0);
                f32x4 sv = v4 + bv;
                bf16x4 ov = {(bf16_t)fmaxf(sv[0], 0.0f), (bf16_t)fmaxf(sv[1], 0.0f),
                             (bf16_t)fmaxf(sv[2], 0.0f), (bf16_t)fmaxf(sv[3], 0.0f)};
                *(bf16x4*)(o + (size_t)row * N + col0) = ov;
            }
        }
}

// ---------------- attention (R16 config): ALiBi-sparse + block-cooperative contiguous zero-fill ----------------
__global__ __launch_bounds__(512, 4) void attn_kernel(const bf16_t* __restrict__ q, const bf16_t* __restrict__ k,
                                                      const bf16_t* __restrict__ vT, float* __restrict__ attn_out,
                                                      bf16_t* __restrict__ o_out) {
    __shared__ __attribute__((aligned(16))) bf16_t Kb[2][64][64];     // rows=s, XOR-swizzled
    __shared__ __attribute__((aligned(16))) bf16_t Vb[2][64][64];     // rows=hs, XOR-swizzled
    __shared__ __attribute__((aligned(16))) bf16_t p_lds[8][16][72];  // [wave][t-local][s-local]
    int bid0 = blockIdx.x;
    int bid = (bid0 & 7) * 64 + (bid0 >> 3);  // colocate same-bh blocks per XCD (K/V L2 reuse)
    int bh = bid >> 4, tb = bid & 15;
    int b = bh >> 3, h = bh & 7;
    int tid = threadIdx.x, lane = tid & 63, w = tid >> 6;
    int r15 = lane & 15, g = lane >> 4;
    int l8 = lane & 7, lr8 = lane >> 3;
    int t0 = tb * 128 + w * 16;
    const bf16_t* qb = q + (size_t)bh * TT * HS;
    const bf16_t* kb = k + (size_t)bh * TT * HS;
    const bf16_t* vb = vT + (size_t)bh * HS * TT;

    int stg_b = (l8 * 16) ^ (lr8 << 4);  // pre-swizzled source byte-in-row

    auto stageK = [&](int buf, int s0) {
        GLD16(kb + (size_t)(s0 + w * 8 + lr8) * HS + (stg_b >> 1), &Kb[buf][w * 8][0]);
    };
    auto stageV = [&](int buf, int s0) {
        GLD16(vb + (size_t)(w * 8 + lr8) * TT + s0 + (stg_b >> 1), &Vb[buf][w * 8][0]);
    };
    auto readKV = [&](const bf16_t* base, int cf, int kk) -> bf16x8 {
        int row = cf * 16 + r15;
        int bo = (kk * 64 + g * 16) ^ ((row & 7) << 4);
        return *(const bf16x8*)((const char*)base + row * 128 + bo);
    };

    bf16x8 aq[2];  // Q fragment (B-operand): lane r15 -> t row, k = hs
#pragma unroll
    for (int kk = 0; kk < 2; ++kk)
        aq[kk] = *(const bf16x8*)&qb[(size_t)(t0 + r15) * HS + kk * 32 + g * 8];

    const float scale2 = 0.125f * 1.44269504f;
    const float slope2 = 0.5f * (h + 1) * 1.44269504f;
    int n_act = min(32, (int)(202.0f / slope2) / 64 + 1);

    // ---- pass 1: l[t=r15] partials over active tiles only ----
    float lreg = 0.0f;
    stageK(0, 0);
    for (int t = 0; t < n_act; ++t) {
        __syncthreads();
        if (t + 1 < n_act) stageK((t + 1) & 1, (t + 1) * 64);
        const bf16_t* Kbase = &Kb[t & 1][0][0];
        f32x4 sacc[4] = {};
        __builtin_amdgcn_s_setprio(1);
#pragma unroll
        for (int kk = 0; kk < 2; ++kk)
#pragma unroll
            for (int cf = 0; cf < 4; ++cf) {
                bf16x8 bk = readKV(Kbase, cf, kk);
                sacc[cf] = MFMA16(bk, aq[kk], sacc[cf]);  // swapped: D[s][t]
            }
        __builtin_amdgcn_s_setprio(0);
        float alb = -slope2 * (float)(t * 64 + g * 4);
#pragma unroll
        for (int cf = 0; cf < 4; ++cf) {
            float alc = alb - slope2 * (16.0f * cf);
#pragma unroll
            for (int r = 0; r < 4; ++r)
                lreg += __builtin_amdgcn_exp2f(fmaf(sacc[cf][r], scale2, alc - slope2 * r));
        }
    }
    lreg += __shfl_xor(lreg, 16, 64);
    lreg += __shfl_xor(lreg, 32, 64);
    float lr2 = -__builtin_amdgcn_logf(lreg);  // log2(1/l), folded into the exponent below

    // ---- pass 2: active tiles: recompute S^T, store normalized P, PV ----
    __syncthreads();  // all waves done reading pass-1 buffers before restage (n_act may be odd)
    f32x4 oacc[4] = {};
    float* aout = attn_out + (size_t)(h * BB + b) * TT * TT;
    stageK(0, 0);
    stageV(0, 0);
    asm volatile("s_waitcnt vmcnt(0)\n\ts_barrier" ::: "memory");
    __builtin_amdgcn_sched_barrier(0);
    for (int t = 0; t < n_act; ++t) {
        if (t + 1 < n_act) { stageK((t + 1) & 1, (t + 1) * 64); stageV((t + 1) & 1, (t + 1) * 64); }
        const bf16_t* Kbase = &Kb[t & 1][0][0];
        const bf16_t* Vbase = &Vb[t & 1][0][0];
        f32x4 sacc[4] = {};
        __builtin_amdgcn_s_setprio(1);
#pragma unroll
        for (int kk = 0; kk < 2; ++kk)
#pragma unroll
            for (int cf = 0; cf < 4; ++cf) {
                bf16x8 bk = readKV(Kbase, cf, kk);
                sacc[cf] = MFMA16(bk, aq[kk], sacc[cf]);
            }
        __builtin_amdgcn_s_setprio(0);
        int s0 = t * 64;
        float alb = lr2 - slope2 * (float)(s0 + g * 4);
        float* arow = aout + (size_t)(t0 + r15) * TT + s0 + g * 4;
#pragma unroll
        for (int cf = 0; cf < 4; ++cf) {
            float alc = alb - slope2 * (16.0f * cf);
            f32x4 pv;
#pragma unroll
            for (int r = 0; r < 4; ++r)
                pv[r] = __builtin_amdgcn_exp2f(fmaf(sacc[cf][r], scale2, alc - slope2 * r));
            *(f32x4*)(arow + cf * 16) = pv;  // 4 consecutive s: dwordx4
            bf16x4 pb = {(bf16_t)pv[0], (bf16_t)pv[1], (bf16_t)pv[2], (bf16_t)pv[3]};
            *(bf16x4*)&p_lds[w][r15][cf * 16 + g * 4] = pb;  // [t][s] layout for PV A-frag
        }
        // p_lds is per-wave: wave-local LDS ordering suffices
        asm volatile("s_waitcnt lgkmcnt(0)" ::: "memory");
        __builtin_amdgcn_sched_barrier(0);
        __builtin_amdgcn_s_setprio(1);
#pragma unroll
        for (int ks = 0; ks < 2; ++ks) {
            bf16x8 pa = *(const bf16x8*)((const char*)&p_lds[w][0][0] + r15 * 144 + ks * 64 + g * 16);
#pragma unroll
            for (int cf = 0; cf < 4; ++cf) {
                bf16x8 bv = readKV(Vbase, cf, ks);
                oacc[cf] = MFMA16(pa, bv, oacc[cf]);
            }
        }
        __builtin_amdgcn_s_setprio(0);
        if (t + 1 < n_act) {
            asm volatile("s_waitcnt vmcnt(4)\n\ts_barrier" ::: "memory");
            __builtin_amdgcn_sched_barrier(0);
        }
    }
#pragma unroll
    for (int cf = 0; cf < 4; ++cf)
#pragma unroll
        for (int r = 0; r < 4; ++r) {
            int t = t0 + g * 4 + r;
            o_out[((size_t)(b * TT + t)) * DD + h * HS + cf * 16 + r15] = (bf16_t)oacc[cf][r];
        }

    // ---- zero-fill s in [n_act*64, TT): block-cooperative, fully contiguous per row ----
    int s_act = n_act * 64;
    int zc = TT - s_act;
    f32x4 z = {0.0f, 0.0f, 0.0f, 0.0f};
    int c = tid * 4;
    if (c < zc) {
        float* zbase = aout + (size_t)(tb * 128) * TT + s_act + c;
        for (int r = 0; r < 128; ++r) *(f32x4*)(zbase + (size_t)r * TT) = z;
    }
}

// ---------------- launch ----------------
extern "C" void kernel_launch(void* const* d_in, const int* in_sizes, int n_in, void* d_out, int out_size,
                              void* d_ws, size_t ws_size, hipStream_t stream) {
    const float* x = (const float*)d_in[0];
    const float* Wq = (const float*)d_in[1];
    const float* Wk = (const float*)d_in[2];
    const float* Wv = (const float*)d_in[3];
    const float* Wp = (const float*)d_in[4];
    const float* bp = (const float*)d_in[5];
    const float* W1 = (const float*)d_in[6];
    const float* b1 = (const float*)d_in[7];
    const float* W2 = (const float*)d_in[8];
    const float* b2 = (const float*)d_in[9];
    const float* g1 = (const float*)d_in[10];
    const float* be1 = (const float*)d_in[11];
    const float* g2 = (const float*)d_in[12];
    const float* be2 = (const float*)d_in[13];

    float* out_x = (float*)d_out;
    float* out_attn = out_x + (size_t)BT * DD;

    char* ws = (char*)d_ws;
    bf16_t* hn = (bf16_t*)(ws);                    // 8MB [8192][512]; reused as h2
    bf16_t* qkv = (bf16_t*)(ws + (8ull << 20));    // 24MB: q,k [bh][t][hs]; vT [bh][hs][t]
    bf16_t* ao = (bf16_t*)(ws + (32ull << 20));    // 8MB attn output, [b][t][h*64+hs]
    bf16_t* ff1 = (bf16_t*)(ws + (8ull << 20));    // 32MB, overlaps qkv+ao (both dead by then)
    float* x1 = (float*)(ws + (40ull << 20));      // 16MB fp32
    bf16_t* Wqkv = (bf16_t*)(ws + (56ull << 20));  // 1.5MB
    bf16_t* Wpt = (bf16_t*)(ws + (58ull << 20));   // 0.5MB
    bf16_t* W1t = (bf16_t*)(ws + (59ull << 20));   // 2MB
    bf16_t* W2t = (bf16_t*)(ws + (61ull << 20));   // 2MB
    bf16_t* qq = qkv;
    bf16_t* kk = qkv + 4194304;
    bf16_t* vT = qkv + 8388608;

    pack_fused<<<3072, 256, 0, stream>>>(Wq, Wk, Wv, Wp, W1, W2, Wqkv, Wpt, W1t, W2t);

    ln_kernel<<<BT, 128, 0, stream>>>(x, g1, be1, hn);
    // DIAGNOSTIC (R18): each GEMM launched twice — idempotent (pure functions, distinct outputs).
    // dur_us delta vs R16 (243.0) == total GEMM-suite steady-state duration.
    gemm_bt<0, 128, 32><<<dim3(64, 12), 256, 0, stream>>>(hn, Wqkv, 1536, 512, nullptr, nullptr, qkv);
    gemm_bt<0, 128, 32><<<dim3(64, 12), 256, 0, stream>>>(hn, Wqkv, 1536, 512, nullptr, nullptr, qkv);
    attn_kernel<<<512, 512, 0, stream>>>(qq, kk, vT, out_attn, ao);
    gemm_bt<1, 64, 64><<<dim3(64, 8), 256, 0, stream>>>(ao, Wpt, 512, 512, bp, x, x1);
    gemm_bt<1, 64, 64><<<dim3(64, 8), 256, 0, stream>>>(ao, Wpt, 512, 512, bp, x, x1);
    ln_kernel<<<BT, 128, 0, stream>>>(x1, g2, be2, hn);
    gemm_bt<2, 128, 32><<<dim3(64, 16), 256, 0, stream>>>(hn, W1t, 2048, 512, b1, nullptr, ff1);
    gemm_bt<2, 128, 32><<<dim3(64, 16), 256, 0, stream>>>(hn, W1t, 2048, 512, b1, nullptr, ff1);
    gemm_bt<1, 64, 64><<<dim3(64, 8), 256, 0, stream>>>(ff1, W2t, 512, 2048, b2, x1, out_x);
    gemm_bt<1, 64, 64><<<dim3(64, 8), 256, 0, stream>>>(ff1, W2t, 512, 2048, b2, x1, out_x);
}

// Round 19
// 241.778 us; speedup vs baseline: 1.3750x; 1.3750x over previous
//
#include <hip/hip_runtime.h>

typedef __bf16 bf16_t;
typedef __bf16 bf16x8 __attribute__((ext_vector_type(8)));
typedef __bf16 bf16x4 __attribute__((ext_vector_type(4)));
typedef float f32x4 __attribute__((ext_vector_type(4)));

typedef __attribute__((address_space(1))) const unsigned int as1_u32;
typedef __attribute__((address_space(3))) unsigned int as3_u32;

#define MFMA16(a, b, c) __builtin_amdgcn_mfma_f32_16x16x32_bf16((a), (b), (c), 0, 0, 0)
#define GLD16(src, dst) __builtin_amdgcn_global_load_lds((as1_u32*)(src), (as3_u32*)(dst), 16, 0, 0)

#define BB 4
#define TT 2048
#define DD 512
#define HH 8
#define HS 64
#define BT (BB * TT) /* 8192 */

// ---------------- fused coalesced weight packing (32x32 LDS tile transpose) ----------------
__global__ __launch_bounds__(256) void pack_fused(const float* __restrict__ Wq, const float* __restrict__ Wk,
                                                  const float* __restrict__ Wv, const float* __restrict__ Wp,
                                                  const float* __restrict__ W1, const float* __restrict__ W2,
                                                  bf16_t* __restrict__ Wqkv, bf16_t* __restrict__ Wpt,
                                                  bf16_t* __restrict__ W1t, bf16_t* __restrict__ W2t) {
    __shared__ float tile[32][33];
    int bx = blockIdx.x;
    const float* src;
    bf16_t* dst;
    int sStride, dStride, tk, tn;
    if (bx < 768) {
        int hs_t = bx & 1, d_t = (bx >> 1) & 15, h = (bx >> 5) & 7, which = bx >> 8;
        const float* W = (which == 0) ? Wq : (which == 1) ? Wk : Wv;
        src = W + (size_t)h * DD * HS;
        dst = Wqkv + (size_t)(which * 512 + h * 64) * DD;
        sStride = HS; dStride = DD; tk = d_t; tn = hs_t;
    } else if (bx < 1024) {
        int r = bx - 768;
        src = Wp; dst = Wpt; sStride = 512; dStride = 512; tn = r & 15; tk = r >> 4;
    } else if (bx < 2048) {
        int r = bx - 1024;
        src = W1; dst = W1t; sStride = 2048; dStride = 512; tn = r & 63; tk = r >> 6;
    } else {
        int r = bx - 2048;
        src = W2; dst = W2t; sStride = 512; dStride = 2048; tn = r & 15; tk = r >> 4;
    }
    int tx = threadIdx.x & 31, ty = threadIdx.x >> 5;
#pragma unroll
    for (int i = 0; i < 4; ++i)
        tile[ty + i * 8][tx] = src[(size_t)(tk * 32 + ty + i * 8) * sStride + tn * 32 + tx];
    __syncthreads();
#pragma unroll
    for (int i = 0; i < 4; ++i)
        dst[(size_t)(tn * 32 + ty + i * 8) * dStride + tk * 32 + tx] = (bf16_t)tile[tx][ty + i * 8];
}

// ---------------- layernorm: barrier-free, one wave per row ----------------
__global__ __launch_bounds__(256) void ln_kernel(const float* __restrict__ in, const float* __restrict__ g,
                                                 const float* __restrict__ be, bf16_t* __restrict__ out) {
    int row = blockIdx.x * 4 + (threadIdx.x >> 6);
    int lane = threadIdx.x & 63;
    const float* rp = in + (size_t)row * DD;
    float4 v0 = *(const float4*)(rp + lane * 4);
    float4 v1 = *(const float4*)(rp + 256 + lane * 4);
    float s = v0.x + v0.y + v0.z + v0.w + v1.x + v1.y + v1.z + v1.w;
    float sq = v0.x * v0.x + v0.y * v0.y + v0.z * v0.z + v0.w * v0.w +
               v1.x * v1.x + v1.y * v1.y + v1.z * v1.z + v1.w * v1.w;
#pragma unroll
    for (int d = 1; d < 64; d <<= 1) {
        s += __shfl_xor(s, d, 64);
        sq += __shfl_xor(sq, d, 64);
    }
    float mu = s * (1.0f / DD);
    float var = sq * (1.0f / DD) - mu * mu;
    float rstd = rsqrtf(var + 1e-5f);
    float4 g0 = *(const float4*)(g + lane * 4);
    float4 g1 = *(const float4*)(g + 256 + lane * 4);
    float4 b0 = *(const float4*)(be + lane * 4);
    float4 b1 = *(const float4*)(be + 256 + lane * 4);
    bf16x4 o0, o1;
    o0[0] = (bf16_t)((v0.x - mu) * rstd * g0.x + b0.x);
    o0[1] = (bf16_t)((v0.y - mu) * rstd * g0.y + b0.y);
    o0[2] = (bf16_t)((v0.z - mu) * rstd * g0.z + b0.z);
    o0[3] = (bf16_t)((v0.w - mu) * rstd * g0.w + b0.w);
    o1[0] = (bf16_t)((v1.x - mu) * rstd * g1.x + b1.x);
    o1[1] = (bf16_t)((v1.y - mu) * rstd * g1.y + b1.y);
    o1[2] = (bf16_t)((v1.z - mu) * rstd * g1.z + b1.z);
    o1[3] = (bf16_t)((v1.w - mu) * rstd * g1.w + b1.w);
    *(bf16x4*)(out + (size_t)row * DD + lane * 4) = o0;
    *(bf16x4*)(out + (size_t)row * DD + 256 + lane * 4) = o1;
}

// ---------------- 128xBN bf16 GEMM, 2-phase double-buffered, BK=32 or 64, XCD-chunked ----------------
// EPI 0: QKV scatter. EPI 1: +bias+resid fp32. EPI 2: +bias ReLU bf16.
template <int EPI, int BN, int BK>
__global__ __launch_bounds__(256) void gemm_bt(const bf16_t* __restrict__ A, const bf16_t* __restrict__ Bt,
                                               int N, int K, const float* __restrict__ bias,
                                               const float* __restrict__ resid, void* __restrict__ outp) {
    __shared__ __attribute__((aligned(16))) bf16_t As[2][128][BK];
    __shared__ __attribute__((aligned(16))) bf16_t Bs[2][BN][BK];
    constexpr int WM = (BN == 128) ? 64 : 32;
    constexpr int AI = WM / 16;
    int lin = blockIdx.y * 64 + blockIdx.x;
    int total = gridDim.y * 64;
    int lin2 = (lin & 7) * (total >> 3) + (lin >> 3);
    int Nb = gridDim.y;
    int m0 = (lin2 / Nb) * 128, n0 = (lin2 % Nb) * BN;
    int tid = threadIdx.x, lane = tid & 63, w = tid >> 6;
    int wr = (BN == 128) ? (w >> 1) : w;
    int wc = (BN == 128) ? (w & 1) : 0;
    int r15 = lane & 15, g = lane >> 4;
    int l4 = lane & 3, lr = lane >> 2;
    int l8 = lane & 7, lr8 = lane >> 3;
    int src32 = (l4 ^ ((lane >> 3) & 3)) * 8;
    int src64 = ((l8 * 16) ^ (lr8 << 4)) >> 1;

    auto stage = [&](int it, int buf) {
        if constexpr (BK == 32) {
            const bf16_t* Ab = A + (size_t)(m0 + w * 32 + lr) * K + it * 32 + src32;
            GLD16(Ab, &As[buf][w * 32][0]);
            GLD16(Ab + (size_t)16 * K, &As[buf][w * 32 + 16][0]);
            if constexpr (BN == 128) {
                const bf16_t* Bb = Bt + (size_t)(n0 + w * 32 + lr) * K + it * 32 + src32;
                GLD16(Bb, &Bs[buf][w * 32][0]);
                GLD16(Bb + (size_t)16 * K, &Bs[buf][w * 32 + 16][0]);
            } else {
                const bf16_t* Bb = Bt + (size_t)(n0 + w * 16 + lr) * K + it * 32 + src32;
                GLD16(Bb, &Bs[buf][w * 16][0]);
            }
        } else {
#pragma unroll
            for (int i = 0; i < 4; ++i)
                GLD16(A + (size_t)(m0 + w * 32 + i * 8 + lr8) * K + it * 64 + src64,
                      &As[buf][w * 32 + i * 8][0]);
            if constexpr (BN == 128) {
#pragma unroll
                for (int i = 0; i < 4; ++i)
                    GLD16(Bt + (size_t)(n0 + w * 32 + i * 8 + lr8) * K + it * 64 + src64,
                          &Bs[buf][w * 32 + i * 8][0]);
            } else {
#pragma unroll
                for (int i = 0; i < 2; ++i)
                    GLD16(Bt + (size_t)(n0 + w * 16 + i * 8 + lr8) * K + it * 64 + src64,
                          &Bs[buf][w * 16 + i * 8][0]);
            }
        }
    };

    f32x4 acc[AI][4] = {};
    stage(0, 0);
    asm volatile("s_waitcnt vmcnt(0)\n\ts_barrier" ::: "memory");
    __builtin_amdgcn_sched_barrier(0);
    constexpr int LOGBK = (BK == 32) ? 5 : 6;
    int nit = K >> LOGBK;
    for (int it = 0; it < nit; ++it) {
        int cur = it & 1;
        if (it + 1 < nit) stage(it + 1, cur ^ 1);
        if constexpr (BK == 32) {
            int bo = (g ^ ((r15 >> 1) & 3)) * 16;
            bf16x8 a[AI], bfr[4];
#pragma unroll
            for (int i = 0; i < AI; ++i)
                a[i] = *(const bf16x8*)((const char*)&As[cur][0][0] + (wr * WM + i * 16 + r15) * 64 + bo);
#pragma unroll
            for (int j = 0; j < 4; ++j)
                bfr[j] = *(const bf16x8*)((const char*)&Bs[cur][0][0] + (wc * 64 + j * 16 + r15) * 64 + bo);
#pragma unroll
            for (int i = 0; i < AI; ++i)
#pragma unroll
                for (int j = 0; j < 4; ++j) acc[i][j] = MFMA16(bfr[j], a[i], acc[i][j]);
        } else {
#pragma unroll
            for (int kk = 0; kk < 2; ++kk) {
                int bo = (kk * 64 + g * 16) ^ ((r15 & 7) << 4);
                bf16x8 a[AI], bfr[4];
#pragma unroll
                for (int i = 0; i < AI; ++i)
                    a[i] = *(const bf16x8*)((const char*)&As[cur][0][0] + (wr * WM + i * 16 + r15) * 128 + bo);
#pragma unroll
                for (int j = 0; j < 4; ++j)
                    bfr[j] = *(const bf16x8*)((const char*)&Bs[cur][0][0] + (wc * 64 + j * 16 + r15) * 128 + bo);
#pragma unroll
                for (int i = 0; i < AI; ++i)
#pragma unroll
                    for (int j = 0; j < 4; ++j) acc[i][j] = MFMA16(bfr[j], a[i], acc[i][j]);
            }
        }
        if (it + 1 < nit) {
            asm volatile("s_waitcnt vmcnt(0)\n\ts_barrier" ::: "memory");
            __builtin_amdgcn_sched_barrier(0);
        }
    }
#pragma unroll
    for (int i = 0; i < AI; ++i)
#pragma unroll
        for (int j = 0; j < 4; ++j) {
            int row = m0 + wr * WM + i * 16 + r15;
            int col0 = n0 + wc * 64 + j * 16 + g * 4;
            f32x4 v4 = acc[i][j];
            if constexpr (EPI == 0) {
                bf16_t* o = (bf16_t*)outp;
                int b_ = row >> 11, t_ = row & 2047;
                int which = col0 >> 9, r9 = col0 & 511, h_ = r9 >> 6, hs0 = r9 & 63;
                if (which < 2) {
                    size_t dst = (size_t)which * 4194304 + (((size_t)(b_ * HH + h_)) * TT + t_) * HS + hs0;
                    bf16x4 ov = {(bf16_t)v4[0], (bf16_t)v4[1], (bf16_t)v4[2], (bf16_t)v4[3]};
                    *(bf16x4*)(o + dst) = ov;
                } else {
                    size_t dst = 8388608 + (((size_t)(b_ * HH + h_)) * HS + hs0) * TT + t_;
#pragma unroll
                    for (int r = 0; r < 4; ++r) o[dst + (size_t)r * TT] = (bf16_t)v4[r];
                }
            } else if constexpr (EPI == 1) {
                float* o = (float*)outp;
                size_t off = (size_t)row * N + col0;
                f32x4 bv = *(const f32x4*)(bias + col0);
                f32x4 rv = *(const f32x4*)(resid + off);
                *(f32x4*)(o + off) = v4 + bv + rv;
            } else {
                bf16_t* o = (bf16_t*)outp;
                f32x4 bv = *(const f32x4*)(bias + col0);
                f32x4 sv = v4 + bv;
                bf16x4 ov = {(bf16_t)fmaxf(sv[0], 0.0f), (bf16_t)fmaxf(sv[1], 0.0f),
                             (bf16_t)fmaxf(sv[2], 0.0f), (bf16_t)fmaxf(sv[3], 0.0f)};
                *(bf16x4*)(o + (size_t)row * N + col0) = ov;
            }
        }
}

// ---------------- attention: ALiBi-sparse; single-pass fast path for n_act==1 (h>=4) ----------------
__global__ __launch_bounds__(512, 4) void attn_kernel(const bf16_t* __restrict__ q, const bf16_t* __restrict__ k,
                                                      const bf16_t* __restrict__ vT, float* __restrict__ attn_out,
                                                      bf16_t* __restrict__ o_out) {
    __shared__ __attribute__((aligned(16))) bf16_t Kb[2][64][64];     // rows=s, XOR-swizzled
    __shared__ __attribute__((aligned(16))) bf16_t Vb[2][64][64];     // rows=hs, XOR-swizzled
    __shared__ __attribute__((aligned(16))) bf16_t p_lds[8][16][72];  // [wave][t-local][s-local]
    int bid0 = blockIdx.x;
    int bid = (bid0 & 7) * 64 + (bid0 >> 3);  // colocate same-bh blocks per XCD (K/V L2 reuse)
    int bh = bid >> 4, tb = bid & 15;
    int b = bh >> 3, h = bh & 7;
    int tid = threadIdx.x, lane = tid & 63, w = tid >> 6;
    int r15 = lane & 15, g = lane >> 4;
    int l8 = lane & 7, lr8 = lane >> 3;
    int t0 = tb * 128 + w * 16;
    const bf16_t* qb = q + (size_t)bh * TT * HS;
    const bf16_t* kb = k + (size_t)bh * TT * HS;
    const bf16_t* vb = vT + (size_t)bh * HS * TT;

    int stg_b = (l8 * 16) ^ (lr8 << 4);  // pre-swizzled source byte-in-row

    auto stageK = [&](int buf, int s0) {
        GLD16(kb + (size_t)(s0 + w * 8 + lr8) * HS + (stg_b >> 1), &Kb[buf][w * 8][0]);
    };
    auto stageV = [&](int buf, int s0) {
        GLD16(vb + (size_t)(w * 8 + lr8) * TT + s0 + (stg_b >> 1), &Vb[buf][w * 8][0]);
    };
    auto readKV = [&](const bf16_t* base, int cf, int kk) -> bf16x8 {
        int row = cf * 16 + r15;
        int bo = (kk * 64 + g * 16) ^ ((row & 7) << 4);
        return *(const bf16x8*)((const char*)base + row * 128 + bo);
    };

    bf16x8 aq[2];  // Q fragment (B-operand): lane r15 -> t row, k = hs
#pragma unroll
    for (int kk = 0; kk < 2; ++kk)
        aq[kk] = *(const bf16x8*)&qb[(size_t)(t0 + r15) * HS + kk * 32 + g * 8];

    const float scale2 = 0.125f * 1.44269504f;
    const float slope2 = 0.5f * (h + 1) * 1.44269504f;
    int n_act = min(32, (int)(202.0f / slope2) / 64 + 1);
    float* aout = attn_out + (size_t)(h * BB + b) * TT * TT;
    f32x4 oacc[4] = {};

    if (n_act == 1) {
        // ---- single pass: exp values retained in registers, normalized by rcp(l) ----
        stageK(0, 0);
        stageV(0, 0);
        asm volatile("s_waitcnt vmcnt(0)\n\ts_barrier" ::: "memory");
        __builtin_amdgcn_sched_barrier(0);
        f32x4 sacc[4] = {};
        __builtin_amdgcn_s_setprio(1);
#pragma unroll
        for (int kk = 0; kk < 2; ++kk)
#pragma unroll
            for (int cf = 0; cf < 4; ++cf) {
                bf16x8 bk = readKV(&Kb[0][0][0], cf, kk);
                sacc[cf] = MFMA16(bk, aq[kk], sacc[cf]);  // swapped: D[s][t]
            }
        __builtin_amdgcn_s_setprio(0);
        float lreg = 0.0f;
        float alb = -slope2 * (float)(g * 4);
#pragma unroll
        for (int cf = 0; cf < 4; ++cf) {
            float alc = alb - slope2 * (16.0f * cf);
#pragma unroll
            for (int r = 0; r < 4; ++r) {
                sacc[cf][r] = __builtin_amdgcn_exp2f(fmaf(sacc[cf][r], scale2, alc - slope2 * r));
                lreg += sacc[cf][r];
            }
        }
        lreg += __shfl_xor(lreg, 16, 64);
        lreg += __shfl_xor(lreg, 32, 64);
        float rinv = __builtin_amdgcn_rcpf(lreg);
        float* arow = aout + (size_t)(t0 + r15) * TT + g * 4;
#pragma unroll
        for (int cf = 0; cf < 4; ++cf) {
            f32x4 pv = sacc[cf] * rinv;
            *(f32x4*)(arow + cf * 16) = pv;
            bf16x4 pb = {(bf16_t)pv[0], (bf16_t)pv[1], (bf16_t)pv[2], (bf16_t)pv[3]};
            *(bf16x4*)&p_lds[w][r15][cf * 16 + g * 4] = pb;
        }
        asm volatile("s_waitcnt lgkmcnt(0)" ::: "memory");
        __builtin_amdgcn_sched_barrier(0);
        __builtin_amdgcn_s_setprio(1);
#pragma unroll
        for (int ks = 0; ks < 2; ++ks) {
            bf16x8 pa = *(const bf16x8*)((const char*)&p_lds[w][0][0] + r15 * 144 + ks * 64 + g * 16);
#pragma unroll
            for (int cf = 0; cf < 4; ++cf) {
                bf16x8 bv = readKV(&Vb[0][0][0], cf, ks);
                oacc[cf] = MFMA16(pa, bv, oacc[cf]);
            }
        }
        __builtin_amdgcn_s_setprio(0);
    } else {
        // ---- pass 1: l[t=r15] partials over active tiles ----
        float lreg = 0.0f;
        stageK(0, 0);
        for (int t = 0; t < n_act; ++t) {
            __syncthreads();
            if (t + 1 < n_act) stageK((t + 1) & 1, (t + 1) * 64);
            const bf16_t* Kbase = &Kb[t & 1][0][0];
            f32x4 sacc[4] = {};
            __builtin_amdgcn_s_setprio(1);
#pragma unroll
            for (int kk = 0; kk < 2; ++kk)
#pragma unroll
                for (int cf = 0; cf < 4; ++cf) {
                    bf16x8 bk = readKV(Kbase, cf, kk);
                    sacc[cf] = MFMA16(bk, aq[kk], sacc[cf]);
                }
            __builtin_amdgcn_s_setprio(0);
            float alb = -slope2 * (float)(t * 64 + g * 4);
#pragma unroll
            for (int cf = 0; cf < 4; ++cf) {
                float alc = alb - slope2 * (16.0f * cf);
#pragma unroll
                for (int r = 0; r < 4; ++r)
                    lreg += __builtin_amdgcn_exp2f(fmaf(sacc[cf][r], scale2, alc - slope2 * r));
            }
        }
        lreg += __shfl_xor(lreg, 16, 64);
        lreg += __shfl_xor(lreg, 32, 64);
        float lr2 = -__builtin_amdgcn_logf(lreg);  // log2(1/l)

        // ---- pass 2: recompute S^T, normalize via exponent fold, store, PV ----
        __syncthreads();  // all waves done with pass-1 buffers before restage
        stageK(0, 0);
        stageV(0, 0);
        asm volatile("s_waitcnt vmcnt(0)\n\ts_barrier" ::: "memory");
        __builtin_amdgcn_sched_barrier(0);
        for (int t = 0; t < n_act; ++t) {
            if (t + 1 < n_act) { stageK((t + 1) & 1, (t + 1) * 64); stageV((t + 1) & 1, (t + 1) * 64); }
            const bf16_t* Kbase = &Kb[t & 1][0][0];
            const bf16_t* Vbase = &Vb[t & 1][0][0];
            f32x4 sacc[4] = {};
            __builtin_amdgcn_s_setprio(1);
#pragma unroll
            for (int kk = 0; kk < 2; ++kk)
#pragma unroll
                for (int cf = 0; cf < 4; ++cf) {
                    bf16x8 bk = readKV(Kbase, cf, kk);
                    sacc[cf] = MFMA16(bk, aq[kk], sacc[cf]);
                }
            __builtin_amdgcn_s_setprio(0);
            int s0 = t * 64;
            float alb = lr2 - slope2 * (float)(s0 + g * 4);
            float* arow = aout + (size_t)(t0 + r15) * TT + s0 + g * 4;
#pragma unroll
            for (int cf = 0; cf < 4; ++cf) {
                float alc = alb - slope2 * (16.0f * cf);
                f32x4 pv;
#pragma unroll
                for (int r = 0; r < 4; ++r)
                    pv[r] = __builtin_amdgcn_exp2f(fmaf(sacc[cf][r], scale2, alc - slope2 * r));
                *(f32x4*)(arow + cf * 16) = pv;
                bf16x4 pb = {(bf16_t)pv[0], (bf16_t)pv[1], (bf16_t)pv[2], (bf16_t)pv[3]};
                *(bf16x4*)&p_lds[w][r15][cf * 16 + g * 4] = pb;
            }
            asm volatile("s_waitcnt lgkmcnt(0)" ::: "memory");
            __builtin_amdgcn_sched_barrier(0);
            __builtin_amdgcn_s_setprio(1);
#pragma unroll
            for (int ks = 0; ks < 2; ++ks) {
                bf16x8 pa = *(const bf16x8*)((const char*)&p_lds[w][0][0] + r15 * 144 + ks * 64 + g * 16);
#pragma unroll
                for (int cf = 0; cf < 4; ++cf) {
                    bf16x8 bv = readKV(Vbase, cf, ks);
                    oacc[cf] = MFMA16(pa, bv, oacc[cf]);
                }
            }
            __builtin_amdgcn_s_setprio(0);
            if (t + 1 < n_act) {
                asm volatile("s_waitcnt vmcnt(4)\n\ts_barrier" ::: "memory");
                __builtin_amdgcn_sched_barrier(0);
            }
        }
    }

#pragma unroll
    for (int cf = 0; cf < 4; ++cf)
#pragma unroll
        for (int r = 0; r < 4; ++r) {
            int t = t0 + g * 4 + r;
            o_out[((size_t)(b * TT + t)) * DD + h * HS + cf * 16 + r15] = (bf16_t)oacc[cf][r];
        }

    // ---- zero-fill s in [n_act*64, TT): block-cooperative, fully contiguous per row ----
    int s_act = n_act * 64;
    int zc = TT - s_act;
    f32x4 z = {0.0f, 0.0f, 0.0f, 0.0f};
    int c = tid * 4;
    if (c < zc) {
        float* zbase = aout + (size_t)(tb * 128) * TT + s_act + c;
        for (int r = 0; r < 128; ++r) *(f32x4*)(zbase + (size_t)r * TT) = z;
    }
}

// ---------------- launch ----------------
extern "C" void kernel_launch(void* const* d_in, const int* in_sizes, int n_in, void* d_out, int out_size,
                              void* d_ws, size_t ws_size, hipStream_t stream) {
    const float* x = (const float*)d_in[0];
    const float* Wq = (const float*)d_in[1];
    const float* Wk = (const float*)d_in[2];
    const float* Wv = (const float*)d_in[3];
    const float* Wp = (const float*)d_in[4];
    const float* bp = (const float*)d_in[5];
    const float* W1 = (const float*)d_in[6];
    const float* b1 = (const float*)d_in[7];
    const float* W2 = (const float*)d_in[8];
    const float* b2 = (const float*)d_in[9];
    const float* g1 = (const float*)d_in[10];
    const float* be1 = (const float*)d_in[11];
    const float* g2 = (const float*)d_in[12];
    const float* be2 = (const float*)d_in[13];

    float* out_x = (float*)d_out;
    float* out_attn = out_x + (size_t)BT * DD;

    char* ws = (char*)d_ws;
    bf16_t* hn = (bf16_t*)(ws);                    // 8MB [8192][512]; reused as h2
    bf16_t* qkv = (bf16_t*)(ws + (8ull << 20));    // 24MB: q,k [bh][t][hs]; vT [bh][hs][t]
    bf16_t* ao = (bf16_t*)(ws + (32ull << 20));    // 8MB attn output, [b][t][h*64+hs]
    bf16_t* ff1 = (bf16_t*)(ws + (8ull << 20));    // 32MB, overlaps qkv+ao (both dead by then)
    float* x1 = (float*)(ws + (40ull << 20));      // 16MB fp32
    bf16_t* Wqkv = (bf16_t*)(ws + (56ull << 20));  // 1.5MB
    bf16_t* Wpt = (bf16_t*)(ws + (58ull << 20));   // 0.5MB
    bf16_t* W1t = (bf16_t*)(ws + (59ull << 20));   // 2MB
    bf16_t* W2t = (bf16_t*)(ws + (61ull << 20));   // 2MB
    bf16_t* qq = qkv;
    bf16_t* kk = qkv + 4194304;
    bf16_t* vT = qkv + 8388608;

    pack_fused<<<3072, 256, 0, stream>>>(Wq, Wk, Wv, Wp, W1, W2, Wqkv, Wpt, W1t, W2t);

    ln_kernel<<<BT / 4, 256, 0, stream>>>(x, g1, be1, hn);
    gemm_bt<0, 128, 32><<<dim3(64, 12), 256, 0, stream>>>(hn, Wqkv, 1536, 512, nullptr, nullptr, qkv);
    attn_kernel<<<512, 512, 0, stream>>>(qq, kk, vT, out_attn, ao);
    gemm_bt<1, 64, 64><<<dim3(64, 8), 256, 0, stream>>>(ao, Wpt, 512, 512, bp, x, x1);
    ln_kernel<<<BT / 4, 256, 0, stream>>>(x1, g2, be2, hn);
    gemm_bt<2, 128, 32><<<dim3(64, 16), 256, 0, stream>>>(hn, W1t, 2048, 512, b1, nullptr, ff1);
    gemm_bt<1, 64, 64><<<dim3(64, 8), 256, 0, stream>>>(ff1, W2t, 512, 2048, b2, x1, out_x);
}

// Round 20
// 233.817 us; speedup vs baseline: 1.4218x; 1.0340x over previous
//
#include <hip/hip_runtime.h>

typedef __bf16 bf16_t;
typedef __bf16 bf16x8 __attribute__((ext_vector_type(8)));
typedef __bf16 bf16x4 __attribute__((ext_vector_type(4)));
typedef float f32x4 __attribute__((ext_vector_type(4)));

typedef __attribute__((address_space(1))) const unsigned int as1_u32;
typedef __attribute__((address_space(3))) unsigned int as3_u32;

#define MFMA16(a, b, c) __builtin_amdgcn_mfma_f32_16x16x32_bf16((a), (b), (c), 0, 0, 0)
#define GLD16(src, dst) __builtin_amdgcn_global_load_lds((as1_u32*)(src), (as3_u32*)(dst), 16, 0, 0)

#define BB 4
#define TT 2048
#define DD 512
#define HH 8
#define HS 64
#define BT (BB * TT) /* 8192 */

// ---------------- fused coalesced weight packing (32x32 LDS tile transpose) ----------------
__global__ __launch_bounds__(256) void pack_fused(const float* __restrict__ Wq, const float* __restrict__ Wk,
                                                  const float* __restrict__ Wv, const float* __restrict__ Wp,
                                                  const float* __restrict__ W1, const float* __restrict__ W2,
                                                  bf16_t* __restrict__ Wqkv, bf16_t* __restrict__ Wpt,
                                                  bf16_t* __restrict__ W1t, bf16_t* __restrict__ W2t) {
    __shared__ float tile[32][33];
    int bx = blockIdx.x;
    const float* src;
    bf16_t* dst;
    int sStride, dStride, tk, tn;
    if (bx < 768) {
        int hs_t = bx & 1, d_t = (bx >> 1) & 15, h = (bx >> 5) & 7, which = bx >> 8;
        const float* W = (which == 0) ? Wq : (which == 1) ? Wk : Wv;
        src = W + (size_t)h * DD * HS;
        dst = Wqkv + (size_t)(which * 512 + h * 64) * DD;
        sStride = HS; dStride = DD; tk = d_t; tn = hs_t;
    } else if (bx < 1024) {
        int r = bx - 768;
        src = Wp; dst = Wpt; sStride = 512; dStride = 512; tn = r & 15; tk = r >> 4;
    } else if (bx < 2048) {
        int r = bx - 1024;
        src = W1; dst = W1t; sStride = 2048; dStride = 512; tn = r & 63; tk = r >> 6;
    } else {
        int r = bx - 2048;
        src = W2; dst = W2t; sStride = 512; dStride = 2048; tn = r & 15; tk = r >> 4;
    }
    int tx = threadIdx.x & 31, ty = threadIdx.x >> 5;
#pragma unroll
    for (int i = 0; i < 4; ++i)
        tile[ty + i * 8][tx] = src[(size_t)(tk * 32 + ty + i * 8) * sStride + tn * 32 + tx];
    __syncthreads();
#pragma unroll
    for (int i = 0; i < 4; ++i)
        dst[(size_t)(tn * 32 + ty + i * 8) * dStride + tk * 32 + tx] = (bf16_t)tile[tx][ty + i * 8];
}

// ---------------- layernorm: barrier-free, one wave per row ----------------
__global__ __launch_bounds__(256) void ln_kernel(const float* __restrict__ in, const float* __restrict__ g,
                                                 const float* __restrict__ be, bf16_t* __restrict__ out) {
    int row = blockIdx.x * 4 + (threadIdx.x >> 6);
    int lane = threadIdx.x & 63;
    const float* rp = in + (size_t)row * DD;
    float4 v0 = *(const float4*)(rp + lane * 4);
    float4 v1 = *(const float4*)(rp + 256 + lane * 4);
    float s = v0.x + v0.y + v0.z + v0.w + v1.x + v1.y + v1.z + v1.w;
    float sq = v0.x * v0.x + v0.y * v0.y + v0.z * v0.z + v0.w * v0.w +
               v1.x * v1.x + v1.y * v1.y + v1.z * v1.z + v1.w * v1.w;
#pragma unroll
    for (int d = 1; d < 64; d <<= 1) {
        s += __shfl_xor(s, d, 64);
        sq += __shfl_xor(sq, d, 64);
    }
    float mu = s * (1.0f / DD);
    float var = sq * (1.0f / DD) - mu * mu;
    float rstd = rsqrtf(var + 1e-5f);
    float4 g0 = *(const float4*)(g + lane * 4);
    float4 g1 = *(const float4*)(g + 256 + lane * 4);
    float4 b0 = *(const float4*)(be + lane * 4);
    float4 b1 = *(const float4*)(be + 256 + lane * 4);
    bf16x4 o0, o1;
    o0[0] = (bf16_t)((v0.x - mu) * rstd * g0.x + b0.x);
    o0[1] = (bf16_t)((v0.y - mu) * rstd * g0.y + b0.y);
    o0[2] = (bf16_t)((v0.z - mu) * rstd * g0.z + b0.z);
    o0[3] = (bf16_t)((v0.w - mu) * rstd * g0.w + b0.w);
    o1[0] = (bf16_t)((v1.x - mu) * rstd * g1.x + b1.x);
    o1[1] = (bf16_t)((v1.y - mu) * rstd * g1.y + b1.y);
    o1[2] = (bf16_t)((v1.z - mu) * rstd * g1.z + b1.z);
    o1[3] = (bf16_t)((v1.w - mu) * rstd * g1.w + b1.w);
    *(bf16x4*)(out + (size_t)row * DD + lane * 4) = o0;
    *(bf16x4*)(out + (size_t)row * DD + 256 + lane * 4) = o1;
}

// ---------------- 128xBN bf16 GEMM + heterogeneous attn-zero-fill blocks ----------------
// Compute blocks: blockIdx.x < 64. Fill blocks (blockIdx.x >= 64, when zfill != nullptr):
// zero attn_out's underflow region — overlaps the store pipe with GEMM compute.
template <int EPI, int BN, int BK>
__global__ __launch_bounds__(256) void gemm_bt(const bf16_t* __restrict__ A, const bf16_t* __restrict__ Bt,
                                               int N, int K, const float* __restrict__ bias,
                                               const float* __restrict__ resid, void* __restrict__ outp,
                                               float* __restrict__ zfill, int fu0) {
    __shared__ __attribute__((aligned(16))) bf16_t As[2][128][BK];
    __shared__ __attribute__((aligned(16))) bf16_t Bs[2][BN][BK];
    constexpr int WM = (BN == 128) ? 64 : 32;
    constexpr int AI = WM / 16;
    int tid = threadIdx.x;

    if (blockIdx.x >= 64) {
        // ---- fill block: zero 64 rows of one bh's underflow region ----
        int u = fu0 + blockIdx.y * (gridDim.x - 64) + (blockIdx.x - 64);
        int bh = u >> 5, rg = u & 31;
        int b_ = bh >> 3, h_ = bh & 7;
        float slope2 = 0.5f * (h_ + 1) * 1.44269504f;
        int n_act = min(32, (int)(202.0f / slope2) / 64 + 1);
        int s_act = n_act * 64;
        int zc = TT - s_act;
        float* base = zfill + (size_t)(h_ * BB + b_) * TT * TT + (size_t)(rg * 64) * TT + s_act;
        f32x4 z = {0.0f, 0.0f, 0.0f, 0.0f};
        for (int r = 0; r < 64; ++r)
            for (int c = tid * 4; c < zc; c += 1024)
                *(f32x4*)(base + (size_t)r * TT + c) = z;
        return;
    }

    int lin = blockIdx.y * 64 + blockIdx.x;
    int total = gridDim.y * 64;
    int lin2 = (lin & 7) * (total >> 3) + (lin >> 3);
    int Nb = gridDim.y;
    int m0 = (lin2 / Nb) * 128, n0 = (lin2 % Nb) * BN;
    int lane = tid & 63, w = tid >> 6;
    int wr = (BN == 128) ? (w >> 1) : w;
    int wc = (BN == 128) ? (w & 1) : 0;
    int r15 = lane & 15, g = lane >> 4;
    int l4 = lane & 3, lr = lane >> 2;
    int l8 = lane & 7, lr8 = lane >> 3;
    int src32 = (l4 ^ ((lane >> 3) & 3)) * 8;
    int src64 = ((l8 * 16) ^ (lr8 << 4)) >> 1;

    auto stage = [&](int it, int buf) {
        if constexpr (BK == 32) {
            const bf16_t* Ab = A + (size_t)(m0 + w * 32 + lr) * K + it * 32 + src32;
            GLD16(Ab, &As[buf][w * 32][0]);
            GLD16(Ab + (size_t)16 * K, &As[buf][w * 32 + 16][0]);
            if constexpr (BN == 128) {
                const bf16_t* Bb = Bt + (size_t)(n0 + w * 32 + lr) * K + it * 32 + src32;
                GLD16(Bb, &Bs[buf][w * 32][0]);
                GLD16(Bb + (size_t)16 * K, &Bs[buf][w * 32 + 16][0]);
            } else {
                const bf16_t* Bb = Bt + (size_t)(n0 + w * 16 + lr) * K + it * 32 + src32;
                GLD16(Bb, &Bs[buf][w * 16][0]);
            }
        } else {
#pragma unroll
            for (int i = 0; i < 4; ++i)
                GLD16(A + (size_t)(m0 + w * 32 + i * 8 + lr8) * K + it * 64 + src64,
                      &As[buf][w * 32 + i * 8][0]);
            if constexpr (BN == 128) {
#pragma unroll
                for (int i = 0; i < 4; ++i)
                    GLD16(Bt + (size_t)(n0 + w * 32 + i * 8 + lr8) * K + it * 64 + src64,
                          &Bs[buf][w * 32 + i * 8][0]);
            } else {
#pragma unroll
                for (int i = 0; i < 2; ++i)
                    GLD16(Bt + (size_t)(n0 + w * 16 + i * 8 + lr8) * K + it * 64 + src64,
                          &Bs[buf][w * 16 + i * 8][0]);
            }
        }
    };

    f32x4 acc[AI][4] = {};
    stage(0, 0);
    asm volatile("s_waitcnt vmcnt(0)\n\ts_barrier" ::: "memory");
    __builtin_amdgcn_sched_barrier(0);
    constexpr int LOGBK = (BK == 32) ? 5 : 6;
    int nit = K >> LOGBK;
    for (int it = 0; it < nit; ++it) {
        int cur = it & 1;
        if (it + 1 < nit) stage(it + 1, cur ^ 1);
        if constexpr (BK == 32) {
            int bo = (g ^ ((r15 >> 1) & 3)) * 16;
            bf16x8 a[AI], bfr[4];
#pragma unroll
            for (int i = 0; i < AI; ++i)
                a[i] = *(const bf16x8*)((const char*)&As[cur][0][0] + (wr * WM + i * 16 + r15) * 64 + bo);
#pragma unroll
            for (int j = 0; j < 4; ++j)
                bfr[j] = *(const bf16x8*)((const char*)&Bs[cur][0][0] + (wc * 64 + j * 16 + r15) * 64 + bo);
#pragma unroll
            for (int i = 0; i < AI; ++i)
#pragma unroll
                for (int j = 0; j < 4; ++j) acc[i][j] = MFMA16(bfr[j], a[i], acc[i][j]);
        } else {
#pragma unroll
            for (int kk = 0; kk < 2; ++kk) {
                int bo = (kk * 64 + g * 16) ^ ((r15 & 7) << 4);
                bf16x8 a[AI], bfr[4];
#pragma unroll
                for (int i = 0; i < AI; ++i)
                    a[i] = *(const bf16x8*)((const char*)&As[cur][0][0] + (wr * WM + i * 16 + r15) * 128 + bo);
#pragma unroll
                for (int j = 0; j < 4; ++j)
                    bfr[j] = *(const bf16x8*)((const char*)&Bs[cur][0][0] + (wc * 64 + j * 16 + r15) * 128 + bo);
#pragma unroll
                for (int i = 0; i < AI; ++i)
#pragma unroll
                    for (int j = 0; j < 4; ++j) acc[i][j] = MFMA16(bfr[j], a[i], acc[i][j]);
            }
        }
        if (it + 1 < nit) {
            asm volatile("s_waitcnt vmcnt(0)\n\ts_barrier" ::: "memory");
            __builtin_amdgcn_sched_barrier(0);
        }
    }
#pragma unroll
    for (int i = 0; i < AI; ++i)
#pragma unroll
        for (int j = 0; j < 4; ++j) {
            int row = m0 + wr * WM + i * 16 + r15;
            int col0 = n0 + wc * 64 + j * 16 + g * 4;
            f32x4 v4 = acc[i][j];
            if constexpr (EPI == 0) {
                bf16_t* o = (bf16_t*)outp;
                int b_ = row >> 11, t_ = row & 2047;
                int which = col0 >> 9, r9 = col0 & 511, h_ = r9 >> 6, hs0 = r9 & 63;
                if (which < 2) {
                    size_t dst = (size_t)which * 4194304 + (((size_t)(b_ * HH + h_)) * TT + t_) * HS + hs0;
                    bf16x4 ov = {(bf16_t)v4[0], (bf16_t)v4[1], (bf16_t)v4[2], (bf16_t)v4[3]};
                    *(bf16x4*)(o + dst) = ov;
                } else {
                    size_t dst = 8388608 + (((size_t)(b_ * HH + h_)) * HS + hs0) * TT + t_;
#pragma unroll
                    for (int r = 0; r < 4; ++r) o[dst + (size_t)r * TT] = (bf16_t)v4[r];
                }
            } else if constexpr (EPI == 1) {
                float* o = (float*)outp;
                size_t off = (size_t)row * N + col0;
                f32x4 bv = *(const f32x4*)(bias + col0);
                f32x4 rv = *(const f32x4*)(resid + off);
                *(f32x4*)(o + off) = v4 + bv + rv;
            } else {
                bf16_t* o = (bf16_t*)outp;
                f32x4 bv = *(const f32x4*)(bias + col0);
                f32x4 sv = v4 + bv;
                bf16x4 ov = {(bf16_t)fmaxf(sv[0], 0.0f), (bf16_t)fmaxf(sv[1], 0.0f),
                             (bf16_t)fmaxf(sv[2], 0.0f), (bf16_t)fmaxf(sv[3], 0.0f)};
                *(bf16x4*)(o + (size_t)row * N + col0) = ov;
            }
        }
}

// ---------------- attention: ALiBi-sparse, active region only (fill moved to GEMM kernels) ----------------
__global__ __launch_bounds__(512, 4) void attn_kernel(const bf16_t* __restrict__ q, const bf16_t* __restrict__ k,
                                                      const bf16_t* __restrict__ vT, float* __restrict__ attn_out,
                                                      bf16_t* __restrict__ o_out) {
    __shared__ __attribute__((aligned(16))) bf16_t Kb[2][64][64];     // rows=s, XOR-swizzled
    __shared__ __attribute__((aligned(16))) bf16_t Vb[2][64][64];     // rows=hs, XOR-swizzled
    __shared__ __attribute__((aligned(16))) bf16_t p_lds[8][16][72];  // [wave][t-local][s-local]
    int bid0 = blockIdx.x;
    int bid = (bid0 & 7) * 64 + (bid0 >> 3);  // colocate same-bh blocks per XCD (K/V L2 reuse)
    int bh = bid >> 4, tb = bid & 15;
    int b = bh >> 3, h = bh & 7;
    int tid = threadIdx.x, lane = tid & 63, w = tid >> 6;
    int r15 = lane & 15, g = lane >> 4;
    int l8 = lane & 7, lr8 = lane >> 3;
    int t0 = tb * 128 + w * 16;
    const bf16_t* qb = q + (size_t)bh * TT * HS;
    const bf16_t* kb = k + (size_t)bh * TT * HS;
    const bf16_t* vb = vT + (size_t)bh * HS * TT;

    int stg_b = (l8 * 16) ^ (lr8 << 4);  // pre-swizzled source byte-in-row

    auto stageK = [&](int buf, int s0) {
        GLD16(kb + (size_t)(s0 + w * 8 + lr8) * HS + (stg_b >> 1), &Kb[buf][w * 8][0]);
    };
    auto stageV = [&](int buf, int s0) {
        GLD16(vb + (size_t)(w * 8 + lr8) * TT + s0 + (stg_b >> 1), &Vb[buf][w * 8][0]);
    };
    auto readKV = [&](const bf16_t* base, int cf, int kk) -> bf16x8 {
        int row = cf * 16 + r15;
        int bo = (kk * 64 + g * 16) ^ ((row & 7) << 4);
        return *(const bf16x8*)((const char*)base + row * 128 + bo);
    };

    bf16x8 aq[2];  // Q fragment (B-operand): lane r15 -> t row, k = hs
#pragma unroll
    for (int kk = 0; kk < 2; ++kk)
        aq[kk] = *(const bf16x8*)&qb[(size_t)(t0 + r15) * HS + kk * 32 + g * 8];

    const float scale2 = 0.125f * 1.44269504f;
    const float slope2 = 0.5f * (h + 1) * 1.44269504f;
    int n_act = min(32, (int)(202.0f / slope2) / 64 + 1);
    float* aout = attn_out + (size_t)(h * BB + b) * TT * TT;
    f32x4 oacc[4] = {};

    if (n_act == 1) {
        // ---- single pass: exp values retained in registers, normalized by rcp(l) ----
        stageK(0, 0);
        stageV(0, 0);
        asm volatile("s_waitcnt vmcnt(0)\n\ts_barrier" ::: "memory");
        __builtin_amdgcn_sched_barrier(0);
        f32x4 sacc[4] = {};
        __builtin_amdgcn_s_setprio(1);
#pragma unroll
        for (int kk = 0; kk < 2; ++kk)
#pragma unroll
            for (int cf = 0; cf < 4; ++cf) {
                bf16x8 bk = readKV(&Kb[0][0][0], cf, kk);
                sacc[cf] = MFMA16(bk, aq[kk], sacc[cf]);  // swapped: D[s][t]
            }
        __builtin_amdgcn_s_setprio(0);
        float lreg = 0.0f;
        float alb = -slope2 * (float)(g * 4);
#pragma unroll
        for (int cf = 0; cf < 4; ++cf) {
            float alc = alb - slope2 * (16.0f * cf);
#pragma unroll
            for (int r = 0; r < 4; ++r) {
                sacc[cf][r] = __builtin_amdgcn_exp2f(fmaf(sacc[cf][r], scale2, alc - slope2 * r));
                lreg += sacc[cf][r];
            }
        }
        lreg += __shfl_xor(lreg, 16, 64);
        lreg += __shfl_xor(lreg, 32, 64);
        float rinv = __builtin_amdgcn_rcpf(lreg);
        float* arow = aout + (size_t)(t0 + r15) * TT + g * 4;
#pragma unroll
        for (int cf = 0; cf < 4; ++cf) {
            f32x4 pv = sacc[cf] * rinv;
            *(f32x4*)(arow + cf * 16) = pv;
            bf16x4 pb = {(bf16_t)pv[0], (bf16_t)pv[1], (bf16_t)pv[2], (bf16_t)pv[3]};
            *(bf16x4*)&p_lds[w][r15][cf * 16 + g * 4] = pb;
        }
        asm volatile("s_waitcnt lgkmcnt(0)" ::: "memory");
        __builtin_amdgcn_sched_barrier(0);
        __builtin_amdgcn_s_setprio(1);
#pragma unroll
        for (int ks = 0; ks < 2; ++ks) {
            bf16x8 pa = *(const bf16x8*)((const char*)&p_lds[w][0][0] + r15 * 144 + ks * 64 + g * 16);
#pragma unroll
            for (int cf = 0; cf < 4; ++cf) {
                bf16x8 bv = readKV(&Vb[0][0][0], cf, ks);
                oacc[cf] = MFMA16(pa, bv, oacc[cf]);
            }
        }
        __builtin_amdgcn_s_setprio(0);
    } else {
        // ---- pass 1: l[t=r15] partials over active tiles ----
        float lreg = 0.0f;
        stageK(0, 0);
        for (int t = 0; t < n_act; ++t) {
            __syncthreads();
            if (t + 1 < n_act) stageK((t + 1) & 1, (t + 1) * 64);
            const bf16_t* Kbase = &Kb[t & 1][0][0];
            f32x4 sacc[4] = {};
            __builtin_amdgcn_s_setprio(1);
#pragma unroll
            for (int kk = 0; kk < 2; ++kk)
#pragma unroll
                for (int cf = 0; cf < 4; ++cf) {
                    bf16x8 bk = readKV(Kbase, cf, kk);
                    sacc[cf] = MFMA16(bk, aq[kk], sacc[cf]);
                }
            __builtin_amdgcn_s_setprio(0);
            float alb = -slope2 * (float)(t * 64 + g * 4);
#pragma unroll
            for (int cf = 0; cf < 4; ++cf) {
                float alc = alb - slope2 * (16.0f * cf);
#pragma unroll
                for (int r = 0; r < 4; ++r)
                    lreg += __builtin_amdgcn_exp2f(fmaf(sacc[cf][r], scale2, alc - slope2 * r));
            }
        }
        lreg += __shfl_xor(lreg, 16, 64);
        lreg += __shfl_xor(lreg, 32, 64);
        float lr2 = -__builtin_amdgcn_logf(lreg);  // log2(1/l)

        // ---- pass 2: recompute S^T, normalize via exponent fold, store, PV ----
        __syncthreads();  // all waves done with pass-1 buffers before restage
        stageK(0, 0);
        stageV(0, 0);
        asm volatile("s_waitcnt vmcnt(0)\n\ts_barrier" ::: "memory");
        __builtin_amdgcn_sched_barrier(0);
        for (int t = 0; t < n_act; ++t) {
            if (t + 1 < n_act) { stageK((t + 1) & 1, (t + 1) * 64); stageV((t + 1) & 1, (t + 1) * 64); }
            const bf16_t* Kbase = &Kb[t & 1][0][0];
            const bf16_t* Vbase = &Vb[t & 1][0][0];
            f32x4 sacc[4] = {};
            __builtin_amdgcn_s_setprio(1);
#pragma unroll
            for (int kk = 0; kk < 2; ++kk)
#pragma unroll
                for (int cf = 0; cf < 4; ++cf) {
                    bf16x8 bk = readKV(Kbase, cf, kk);
                    sacc[cf] = MFMA16(bk, aq[kk], sacc[cf]);
                }
            __builtin_amdgcn_s_setprio(0);
            int s0 = t * 64;
            float alb = lr2 - slope2 * (float)(s0 + g * 4);
            float* arow = aout + (size_t)(t0 + r15) * TT + s0 + g * 4;
#pragma unroll
            for (int cf = 0; cf < 4; ++cf) {
                float alc = alb - slope2 * (16.0f * cf);
                f32x4 pv;
#pragma unroll
                for (int r = 0; r < 4; ++r)
                    pv[r] = __builtin_amdgcn_exp2f(fmaf(sacc[cf][r], scale2, alc - slope2 * r));
                *(f32x4*)(arow + cf * 16) = pv;
                bf16x4 pb = {(bf16_t)pv[0], (bf16_t)pv[1], (bf16_t)pv[2], (bf16_t)pv[3]};
                *(bf16x4*)&p_lds[w][r15][cf * 16 + g * 4] = pb;
            }
            asm volatile("s_waitcnt lgkmcnt(0)" ::: "memory");
            __builtin_amdgcn_sched_barrier(0);
            __builtin_amdgcn_s_setprio(1);
#pragma unroll
            for (int ks = 0; ks < 2; ++ks) {
                bf16x8 pa = *(const bf16x8*)((const char*)&p_lds[w][0][0] + r15 * 144 + ks * 64 + g * 16);
#pragma unroll
                for (int cf = 0; cf < 4; ++cf) {
                    bf16x8 bv = readKV(Vbase, cf, ks);
                    oacc[cf] = MFMA16(pa, bv, oacc[cf]);
                }
            }
            __builtin_amdgcn_s_setprio(0);
            if (t + 1 < n_act) {
                asm volatile("s_waitcnt vmcnt(4)\n\ts_barrier" ::: "memory");
                __builtin_amdgcn_sched_barrier(0);
            }
        }
    }

#pragma unroll
    for (int cf = 0; cf < 4; ++cf)
#pragma unroll
        for (int r = 0; r < 4; ++r) {
            int t = t0 + g * 4 + r;
            o_out[((size_t)(b * TT + t)) * DD + h * HS + cf * 16 + r15] = (bf16_t)oacc[cf][r];
        }
}

// ---------------- launch ----------------
extern "C" void kernel_launch(void* const* d_in, const int* in_sizes, int n_in, void* d_out, int out_size,
                              void* d_ws, size_t ws_size, hipStream_t stream) {
    const float* x = (const float*)d_in[0];
    const float* Wq = (const float*)d_in[1];
    const float* Wk = (const float*)d_in[2];
    const float* Wv = (const float*)d_in[3];
    const float* Wp = (const float*)d_in[4];
    const float* bp = (const float*)d_in[5];
    const float* W1 = (const float*)d_in[6];
    const float* b1 = (const float*)d_in[7];
    const float* W2 = (const float*)d_in[8];
    const float* b2 = (const float*)d_in[9];
    const float* g1 = (const float*)d_in[10];
    const float* be1 = (const float*)d_in[11];
    const float* g2 = (const float*)d_in[12];
    const float* be2 = (const float*)d_in[13];

    float* out_x = (float*)d_out;
    float* out_attn = out_x + (size_t)BT * DD;

    char* ws = (char*)d_ws;
    bf16_t* hn = (bf16_t*)(ws);                    // 8MB [8192][512]; reused as h2
    bf16_t* qkv = (bf16_t*)(ws + (8ull << 20));    // 24MB: q,k [bh][t][hs]; vT [bh][hs][t]
    bf16_t* ao = (bf16_t*)(ws + (32ull << 20));    // 8MB attn output, [b][t][h*64+hs]
    bf16_t* ff1 = (bf16_t*)(ws + (8ull << 20));    // 32MB, overlaps qkv+ao (both dead by then)
    float* x1 = (float*)(ws + (40ull << 20));      // 16MB fp32
    bf16_t* Wqkv = (bf16_t*)(ws + (56ull << 20));  // 1.5MB
    bf16_t* Wpt = (bf16_t*)(ws + (58ull << 20));   // 0.5MB
    bf16_t* W1t = (bf16_t*)(ws + (59ull << 20));   // 2MB
    bf16_t* W2t = (bf16_t*)(ws + (61ull << 20));   // 2MB
    bf16_t* qq = qkv;
    bf16_t* kk = qkv + 4194304;
    bf16_t* vT = qkv + 8388608;

    pack_fused<<<3072, 256, 0, stream>>>(Wq, Wk, Wv, Wp, W1, W2, Wqkv, Wpt, W1t, W2t);

    ln_kernel<<<BT / 4, 256, 0, stream>>>(x, g1, be1, hn);
    gemm_bt<0, 128, 32><<<dim3(64, 12), 256, 0, stream>>>(hn, Wqkv, 1536, 512, nullptr, nullptr, qkv,
                                                          nullptr, 0);
    attn_kernel<<<512, 512, 0, stream>>>(qq, kk, vT, out_attn, ao);
    // Fill blocks for attn_out's zero region ride along with the post-attn GEMMs:
    // proj: units [0,256)  FFN1: units [256,768)  FFN2: units [768,1024)
    gemm_bt<1, 64, 64><<<dim3(96, 8), 256, 0, stream>>>(ao, Wpt, 512, 512, bp, x, x1, out_attn, 0);
    ln_kernel<<<BT / 4, 256, 0, stream>>>(x1, g2, be2, hn);
    gemm_bt<2, 128, 32><<<dim3(96, 16), 256, 0, stream>>>(hn, W1t, 2048, 512, b1, nullptr, ff1,
                                                          out_attn, 256);
    gemm_bt<1, 64, 64><<<dim3(96, 8), 256, 0, stream>>>(ff1, W2t, 512, 2048, b2, x1, out_x,
                                                        out_attn, 768);
}

// Round 21
// 233.116 us; speedup vs baseline: 1.4261x; 1.0030x over previous
//
#include <hip/hip_runtime.h>

typedef __bf16 bf16_t;
typedef __bf16 bf16x8 __attribute__((ext_vector_type(8)));
typedef __bf16 bf16x4 __attribute__((ext_vector_type(4)));
typedef float f32x4 __attribute__((ext_vector_type(4)));

typedef __attribute__((address_space(1))) const unsigned int as1_u32;
typedef __attribute__((address_space(3))) unsigned int as3_u32;

#define MFMA16(a, b, c) __builtin_amdgcn_mfma_f32_16x16x32_bf16((a), (b), (c), 0, 0, 0)
#define GLD16(src, dst) __builtin_amdgcn_global_load_lds((as1_u32*)(src), (as3_u32*)(dst), 16, 0, 0)

#define BB 4
#define TT 2048
#define DD 512
#define HH 8
#define HS 64
#define BT (BB * TT) /* 8192 */

// ---------------- fused coalesced weight packing (32x32 LDS tile transpose) ----------------
__global__ __launch_bounds__(256) void pack_fused(const float* __restrict__ Wq, const float* __restrict__ Wk,
                                                  const float* __restrict__ Wv, const float* __restrict__ Wp,
                                                  const float* __restrict__ W1, const float* __restrict__ W2,
                                                  bf16_t* __restrict__ Wqkv, bf16_t* __restrict__ Wpt,
                                                  bf16_t* __restrict__ W1t, bf16_t* __restrict__ W2t) {
    __shared__ float tile[32][33];
    int bx = blockIdx.x;
    const float* src;
    bf16_t* dst;
    int sStride, dStride, tk, tn;
    if (bx < 768) {
        int hs_t = bx & 1, d_t = (bx >> 1) & 15, h = (bx >> 5) & 7, which = bx >> 8;
        const float* W = (which == 0) ? Wq : (which == 1) ? Wk : Wv;
        src = W + (size_t)h * DD * HS;
        dst = Wqkv + (size_t)(which * 512 + h * 64) * DD;
        sStride = HS; dStride = DD; tk = d_t; tn = hs_t;
    } else if (bx < 1024) {
        int r = bx - 768;
        src = Wp; dst = Wpt; sStride = 512; dStride = 512; tn = r & 15; tk = r >> 4;
    } else if (bx < 2048) {
        int r = bx - 1024;
        src = W1; dst = W1t; sStride = 2048; dStride = 512; tn = r & 63; tk = r >> 6;
    } else {
        int r = bx - 2048;
        src = W2; dst = W2t; sStride = 512; dStride = 2048; tn = r & 15; tk = r >> 4;
    }
    int tx = threadIdx.x & 31, ty = threadIdx.x >> 5;
#pragma unroll
    for (int i = 0; i < 4; ++i)
        tile[ty + i * 8][tx] = src[(size_t)(tk * 32 + ty + i * 8) * sStride + tn * 32 + tx];
    __syncthreads();
#pragma unroll
    for (int i = 0; i < 4; ++i)
        dst[(size_t)(tn * 32 + ty + i * 8) * dStride + tk * 32 + tx] = (bf16_t)tile[tx][ty + i * 8];
}

// ---------------- layernorm: barrier-free, one wave per row ----------------
__global__ __launch_bounds__(256) void ln_kernel(const float* __restrict__ in, const float* __restrict__ g,
                                                 const float* __restrict__ be, bf16_t* __restrict__ out) {
    int row = blockIdx.x * 4 + (threadIdx.x >> 6);
    int lane = threadIdx.x & 63;
    const float* rp = in + (size_t)row * DD;
    float4 v0 = *(const float4*)(rp + lane * 4);
    float4 v1 = *(const float4*)(rp + 256 + lane * 4);
    float s = v0.x + v0.y + v0.z + v0.w + v1.x + v1.y + v1.z + v1.w;
    float sq = v0.x * v0.x + v0.y * v0.y + v0.z * v0.z + v0.w * v0.w +
               v1.x * v1.x + v1.y * v1.y + v1.z * v1.z + v1.w * v1.w;
#pragma unroll
    for (int d = 1; d < 64; d <<= 1) {
        s += __shfl_xor(s, d, 64);
        sq += __shfl_xor(sq, d, 64);
    }
    float mu = s * (1.0f / DD);
    float var = sq * (1.0f / DD) - mu * mu;
    float rstd = rsqrtf(var + 1e-5f);
    float4 g0 = *(const float4*)(g + lane * 4);
    float4 g1 = *(const float4*)(g + 256 + lane * 4);
    float4 b0 = *(const float4*)(be + lane * 4);
    float4 b1 = *(const float4*)(be + 256 + lane * 4);
    bf16x4 o0, o1;
    o0[0] = (bf16_t)((v0.x - mu) * rstd * g0.x + b0.x);
    o0[1] = (bf16_t)((v0.y - mu) * rstd * g0.y + b0.y);
    o0[2] = (bf16_t)((v0.z - mu) * rstd * g0.z + b0.z);
    o0[3] = (bf16_t)((v0.w - mu) * rstd * g0.w + b0.w);
    o1[0] = (bf16_t)((v1.x - mu) * rstd * g1.x + b1.x);
    o1[1] = (bf16_t)((v1.y - mu) * rstd * g1.y + b1.y);
    o1[2] = (bf16_t)((v1.z - mu) * rstd * g1.z + b1.z);
    o1[3] = (bf16_t)((v1.w - mu) * rstd * g1.w + b1.w);
    *(bf16x4*)(out + (size_t)row * DD + lane * 4) = o0;
    *(bf16x4*)(out + (size_t)row * DD + 256 + lane * 4) = o1;
}

// ---------------- 128xBN bf16 GEMM + heterogeneous attn-zero-fill blocks ----------------
// Compute blocks: blockIdx.x < 64.  Fill blocks (blockIdx.x >= 64, zfill != nullptr):
// zero attn_out's underflow region (address-disjoint from attn's active writes; order-free).
template <int EPI, int BN, int BK>
__global__ __launch_bounds__(256) void gemm_bt(const bf16_t* __restrict__ A, const bf16_t* __restrict__ Bt,
                                               int N, int K, const float* __restrict__ bias,
                                               const float* __restrict__ resid, void* __restrict__ outp,
                                               float* __restrict__ zfill, int fu0) {
    __shared__ __attribute__((aligned(16))) bf16_t As[2][128][BK];
    __shared__ __attribute__((aligned(16))) bf16_t Bs[2][BN][BK];
    constexpr int WM = (BN == 128) ? 64 : 32;
    constexpr int AI = WM / 16;
    int tid = threadIdx.x;

    if (blockIdx.x >= 64) {
        int u = fu0 + blockIdx.y * (gridDim.x - 64) + (blockIdx.x - 64);
        int bh = u >> 5, rg = u & 31;
        int b_ = bh >> 3, h_ = bh & 7;
        float slope2 = 0.5f * (h_ + 1) * 1.44269504f;
        int n_act = min(32, (int)(202.0f / slope2) / 64 + 1);
        int s_act = n_act * 64;
        int zc = TT - s_act;
        float* base = zfill + (size_t)(h_ * BB + b_) * TT * TT + (size_t)(rg * 64) * TT + s_act;
        f32x4 z = {0.0f, 0.0f, 0.0f, 0.0f};
        for (int r = 0; r < 64; ++r)
            for (int c = tid * 4; c < zc; c += 1024)
                *(f32x4*)(base + (size_t)r * TT + c) = z;
        return;
    }

    int lin = blockIdx.y * 64 + blockIdx.x;
    int total = gridDim.y * 64;
    int lin2 = (lin & 7) * (total >> 3) + (lin >> 3);
    int Nb = gridDim.y;
    int m0 = (lin2 / Nb) * 128, n0 = (lin2 % Nb) * BN;
    int lane = tid & 63, w = tid >> 6;
    int wr = (BN == 128) ? (w >> 1) : w;
    int wc = (BN == 128) ? (w & 1) : 0;
    int r15 = lane & 15, g = lane >> 4;
    int l4 = lane & 3, lr = lane >> 2;
    int l8 = lane & 7, lr8 = lane >> 3;
    int src32 = (l4 ^ ((lane >> 3) & 3)) * 8;
    int src64 = ((l8 * 16) ^ (lr8 << 4)) >> 1;

    auto stage = [&](int it, int buf) {
        if constexpr (BK == 32) {
            const bf16_t* Ab = A + (size_t)(m0 + w * 32 + lr) * K + it * 32 + src32;
            GLD16(Ab, &As[buf][w * 32][0]);
            GLD16(Ab + (size_t)16 * K, &As[buf][w * 32 + 16][0]);
            if constexpr (BN == 128) {
                const bf16_t* Bb = Bt + (size_t)(n0 + w * 32 + lr) * K + it * 32 + src32;
                GLD16(Bb, &Bs[buf][w * 32][0]);
                GLD16(Bb + (size_t)16 * K, &Bs[buf][w * 32 + 16][0]);
            } else {
                const bf16_t* Bb = Bt + (size_t)(n0 + w * 16 + lr) * K + it * 32 + src32;
                GLD16(Bb, &Bs[buf][w * 16][0]);
            }
        } else {
#pragma unroll
            for (int i = 0; i < 4; ++i)
                GLD16(A + (size_t)(m0 + w * 32 + i * 8 + lr8) * K + it * 64 + src64,
                      &As[buf][w * 32 + i * 8][0]);
            if constexpr (BN == 128) {
#pragma unroll
                for (int i = 0; i < 4; ++i)
                    GLD16(Bt + (size_t)(n0 + w * 32 + i * 8 + lr8) * K + it * 64 + src64,
                          &Bs[buf][w * 32 + i * 8][0]);
            } else {
#pragma unroll
                for (int i = 0; i < 2; ++i)
                    GLD16(Bt + (size_t)(n0 + w * 16 + i * 8 + lr8) * K + it * 64 + src64,
                          &Bs[buf][w * 16 + i * 8][0]);
            }
        }
    };

    f32x4 acc[AI][4] = {};
    stage(0, 0);
    asm volatile("s_waitcnt vmcnt(0)\n\ts_barrier" ::: "memory");
    __builtin_amdgcn_sched_barrier(0);
    constexpr int LOGBK = (BK == 32) ? 5 : 6;
    int nit = K >> LOGBK;
    for (int it = 0; it < nit; ++it) {
        int cur = it & 1;
        if (it + 1 < nit) stage(it + 1, cur ^ 1);
        if constexpr (BK == 32) {
            int bo = (g ^ ((r15 >> 1) & 3)) * 16;
            bf16x8 a[AI], bfr[4];
#pragma unroll
            for (int i = 0; i < AI; ++i)
                a[i] = *(const bf16x8*)((const char*)&As[cur][0][0] + (wr * WM + i * 16 + r15) * 64 + bo);
#pragma unroll
            for (int j = 0; j < 4; ++j)
                bfr[j] = *(const bf16x8*)((const char*)&Bs[cur][0][0] + (wc * 64 + j * 16 + r15) * 64 + bo);
#pragma unroll
            for (int i = 0; i < AI; ++i)
#pragma unroll
                for (int j = 0; j < 4; ++j) acc[i][j] = MFMA16(bfr[j], a[i], acc[i][j]);
        } else {
#pragma unroll
            for (int kk = 0; kk < 2; ++kk) {
                int bo = (kk * 64 + g * 16) ^ ((r15 & 7) << 4);
                bf16x8 a[AI], bfr[4];
#pragma unroll
                for (int i = 0; i < AI; ++i)
                    a[i] = *(const bf16x8*)((const char*)&As[cur][0][0] + (wr * WM + i * 16 + r15) * 128 + bo);
#pragma unroll
                for (int j = 0; j < 4; ++j)
                    bfr[j] = *(const bf16x8*)((const char*)&Bs[cur][0][0] + (wc * 64 + j * 16 + r15) * 128 + bo);
#pragma unroll
                for (int i = 0; i < AI; ++i)
#pragma unroll
                    for (int j = 0; j < 4; ++j) acc[i][j] = MFMA16(bfr[j], a[i], acc[i][j]);
            }
        }
        if (it + 1 < nit) {
            asm volatile("s_waitcnt vmcnt(0)\n\ts_barrier" ::: "memory");
            __builtin_amdgcn_sched_barrier(0);
        }
    }
#pragma unroll
    for (int i = 0; i < AI; ++i)
#pragma unroll
        for (int j = 0; j < 4; ++j) {
            int row = m0 + wr * WM + i * 16 + r15;
            int col0 = n0 + wc * 64 + j * 16 + g * 4;
            f32x4 v4 = acc[i][j];
            if constexpr (EPI == 0) {
                bf16_t* o = (bf16_t*)outp;
                int b_ = row >> 11, t_ = row & 2047;
                int which = col0 >> 9, r9 = col0 & 511, h_ = r9 >> 6, hs0 = r9 & 63;
                if (which < 2) {
                    size_t dst = (size_t)which * 4194304 + (((size_t)(b_ * HH + h_)) * TT + t_) * HS + hs0;
                    bf16x4 ov = {(bf16_t)v4[0], (bf16_t)v4[1], (bf16_t)v4[2], (bf16_t)v4[3]};
                    *(bf16x4*)(o + dst) = ov;
                } else {
                    size_t dst = 8388608 + (((size_t)(b_ * HH + h_)) * HS + hs0) * TT + t_;
#pragma unroll
                    for (int r = 0; r < 4; ++r) o[dst + (size_t)r * TT] = (bf16_t)v4[r];
                }
            } else if constexpr (EPI == 1) {
                float* o = (float*)outp;
                size_t off = (size_t)row * N + col0;
                f32x4 bv = *(const f32x4*)(bias + col0);
                f32x4 rv = *(const f32x4*)(resid + off);
                *(f32x4*)(o + off) = v4 + bv + rv;
            } else {
                bf16_t* o = (bf16_t*)outp;
                f32x4 bv = *(const f32x4*)(bias + col0);
                f32x4 sv = v4 + bv;
                bf16x4 ov = {(bf16_t)fmaxf(sv[0], 0.0f), (bf16_t)fmaxf(sv[1], 0.0f),
                             (bf16_t)fmaxf(sv[2], 0.0f), (bf16_t)fmaxf(sv[3], 0.0f)};
                *(bf16x4*)(o + (size_t)row * N + col0) = ov;
            }
        }
}

// ---------------- attention: ALiBi-sparse, active region only; XCD-balanced block map ----------------
// tb = ((bid&7)<<1)|((bid>>3)&1), bh = bid>>4  ->  each XCD gets 2 tb-slices of EVERY bh
// (128 active tile-units per XCD, perfectly balanced; active K/V ~1MB so locality is moot).
__global__ __launch_bounds__(512, 4) void attn_kernel(const bf16_t* __restrict__ q, const bf16_t* __restrict__ k,
                                                      const bf16_t* __restrict__ vT, float* __restrict__ attn_out,
                                                      bf16_t* __restrict__ o_out) {
    __shared__ __attribute__((aligned(16))) bf16_t Kb[2][64][64];     // rows=s, XOR-swizzled
    __shared__ __attribute__((aligned(16))) bf16_t Vb[2][64][64];     // rows=hs, XOR-swizzled
    __shared__ __attribute__((aligned(16))) bf16_t p_lds[8][16][72];  // [wave][t-local][s-local]
    int bid0 = blockIdx.x;
    int tb = ((bid0 & 7) << 1) | ((bid0 >> 3) & 1);
    int bh = bid0 >> 4;
    int b = bh >> 3, h = bh & 7;
    int tid = threadIdx.x, lane = tid & 63, w = tid >> 6;
    int r15 = lane & 15, g = lane >> 4;
    int l8 = lane & 7, lr8 = lane >> 3;
    int t0 = tb * 128 + w * 16;
    const bf16_t* qb = q + (size_t)bh * TT * HS;
    const bf16_t* kb = k + (size_t)bh * TT * HS;
    const bf16_t* vb = vT + (size_t)bh * HS * TT;

    int stg_b = (l8 * 16) ^ (lr8 << 4);  // pre-swizzled source byte-in-row

    auto stageK = [&](int buf, int s0) {
        GLD16(kb + (size_t)(s0 + w * 8 + lr8) * HS + (stg_b >> 1), &Kb[buf][w * 8][0]);
    };
    auto stageV = [&](int buf, int s0) {
        GLD16(vb + (size_t)(w * 8 + lr8) * TT + s0 + (stg_b >> 1), &Vb[buf][w * 8][0]);
    };
    auto readKV = [&](const bf16_t* base, int cf, int kk) -> bf16x8 {
        int row = cf * 16 + r15;
        int bo = (kk * 64 + g * 16) ^ ((row & 7) << 4);
        return *(const bf16x8*)((const char*)base + row * 128 + bo);
    };

    bf16x8 aq[2];  // Q fragment (B-operand): lane r15 -> t row, k = hs
#pragma unroll
    for (int kk = 0; kk < 2; ++kk)
        aq[kk] = *(const bf16x8*)&qb[(size_t)(t0 + r15) * HS + kk * 32 + g * 8];

    const float scale2 = 0.125f * 1.44269504f;
    const float slope2 = 0.5f * (h + 1) * 1.44269504f;
    int n_act = min(32, (int)(202.0f / slope2) / 64 + 1);
    float* aout = attn_out + (size_t)(h * BB + b) * TT * TT;
    f32x4 oacc[4] = {};

    if (n_act == 1) {
        // ---- single pass: exp values retained in registers, normalized by rcp(l) ----
        stageK(0, 0);
        stageV(0, 0);
        asm volatile("s_waitcnt vmcnt(0)\n\ts_barrier" ::: "memory");
        __builtin_amdgcn_sched_barrier(0);
        f32x4 sacc[4] = {};
        __builtin_amdgcn_s_setprio(1);
#pragma unroll
        for (int kk = 0; kk < 2; ++kk)
#pragma unroll
            for (int cf = 0; cf < 4; ++cf) {
                bf16x8 bk = readKV(&Kb[0][0][0], cf, kk);
                sacc[cf] = MFMA16(bk, aq[kk], sacc[cf]);  // swapped: D[s][t]
            }
        __builtin_amdgcn_s_setprio(0);
        float lreg = 0.0f;
        float alb = -slope2 * (float)(g * 4);
#pragma unroll
        for (int cf = 0; cf < 4; ++cf) {
            float alc = alb - slope2 * (16.0f * cf);
#pragma unroll
            for (int r = 0; r < 4; ++r) {
                sacc[cf][r] = __builtin_amdgcn_exp2f(fmaf(sacc[cf][r], scale2, alc - slope2 * r));
                lreg += sacc[cf][r];
            }
        }
        lreg += __shfl_xor(lreg, 16, 64);
        lreg += __shfl_xor(lreg, 32, 64);
        float rinv = __builtin_amdgcn_rcpf(lreg);
        float* arow = aout + (size_t)(t0 + r15) * TT + g * 4;
#pragma unroll
        for (int cf = 0; cf < 4; ++cf) {
            f32x4 pv = sacc[cf] * rinv;
            *(f32x4*)(arow + cf * 16) = pv;
            bf16x4 pb = {(bf16_t)pv[0], (bf16_t)pv[1], (bf16_t)pv[2], (bf16_t)pv[3]};
            *(bf16x4*)&p_lds[w][r15][cf * 16 + g * 4] = pb;
        }
        asm volatile("s_waitcnt lgkmcnt(0)" ::: "memory");
        __builtin_amdgcn_sched_barrier(0);
        __builtin_amdgcn_s_setprio(1);
#pragma unroll
        for (int ks = 0; ks < 2; ++ks) {
            bf16x8 pa = *(const bf16x8*)((const char*)&p_lds[w][0][0] + r15 * 144 + ks * 64 + g * 16);
#pragma unroll
            for (int cf = 0; cf < 4; ++cf) {
                bf16x8 bv = readKV(&Vb[0][0][0], cf, ks);
                oacc[cf] = MFMA16(pa, bv, oacc[cf]);
            }
        }
        __builtin_amdgcn_s_setprio(0);
    } else {
        // ---- pass 1: l[t=r15] partials over active tiles ----
        float lreg = 0.0f;
        stageK(0, 0);
        for (int t = 0; t < n_act; ++t) {
            __syncthreads();
            if (t + 1 < n_act) stageK((t + 1) & 1, (t + 1) * 64);
            const bf16_t* Kbase = &Kb[t & 1][0][0];
            f32x4 sacc[4] = {};
            __builtin_amdgcn_s_setprio(1);
#pragma unroll
            for (int kk = 0; kk < 2; ++kk)
#pragma unroll
                for (int cf = 0; cf < 4; ++cf) {
                    bf16x8 bk = readKV(Kbase, cf, kk);
                    sacc[cf] = MFMA16(bk, aq[kk], sacc[cf]);
                }
            __builtin_amdgcn_s_setprio(0);
            float alb = -slope2 * (float)(t * 64 + g * 4);
#pragma unroll
            for (int cf = 0; cf < 4; ++cf) {
                float alc = alb - slope2 * (16.0f * cf);
#pragma unroll
                for (int r = 0; r < 4; ++r)
                    lreg += __builtin_amdgcn_exp2f(fmaf(sacc[cf][r], scale2, alc - slope2 * r));
            }
        }
        lreg += __shfl_xor(lreg, 16, 64);
        lreg += __shfl_xor(lreg, 32, 64);
        float lr2 = -__builtin_amdgcn_logf(lreg);  // log2(1/l)

        // ---- pass 2: recompute S^T, normalize via exponent fold, store, PV ----
        __syncthreads();  // all waves done with pass-1 buffers before restage
        stageK(0, 0);
        stageV(0, 0);
        asm volatile("s_waitcnt vmcnt(0)\n\ts_barrier" ::: "memory");
        __builtin_amdgcn_sched_barrier(0);
        for (int t = 0; t < n_act; ++t) {
            if (t + 1 < n_act) { stageK((t + 1) & 1, (t + 1) * 64); stageV((t + 1) & 1, (t + 1) * 64); }
            const bf16_t* Kbase = &Kb[t & 1][0][0];
            const bf16_t* Vbase = &Vb[t & 1][0][0];
            f32x4 sacc[4] = {};
            __builtin_amdgcn_s_setprio(1);
#pragma unroll
            for (int kk = 0; kk < 2; ++kk)
#pragma unroll
                for (int cf = 0; cf < 4; ++cf) {
                    bf16x8 bk = readKV(Kbase, cf, kk);
                    sacc[cf] = MFMA16(bk, aq[kk], sacc[cf]);
                }
            __builtin_amdgcn_s_setprio(0);
            int s0 = t * 64;
            float alb = lr2 - slope2 * (float)(s0 + g * 4);
            float* arow = aout + (size_t)(t0 + r15) * TT + s0 + g * 4;
#pragma unroll
            for (int cf = 0; cf < 4; ++cf) {
                float alc = alb - slope2 * (16.0f * cf);
                f32x4 pv;
#pragma unroll
                for (int r = 0; r < 4; ++r)
                    pv[r] = __builtin_amdgcn_exp2f(fmaf(sacc[cf][r], scale2, alc - slope2 * r));
                *(f32x4*)(arow + cf * 16) = pv;
                bf16x4 pb = {(bf16_t)pv[0], (bf16_t)pv[1], (bf16_t)pv[2], (bf16_t)pv[3]};
                *(bf16x4*)&p_lds[w][r15][cf * 16 + g * 4] = pb;
            }
            asm volatile("s_waitcnt lgkmcnt(0)" ::: "memory");
            __builtin_amdgcn_sched_barrier(0);
            __builtin_amdgcn_s_setprio(1);
#pragma unroll
            for (int ks = 0; ks < 2; ++ks) {
                bf16x8 pa = *(const bf16x8*)((const char*)&p_lds[w][0][0] + r15 * 144 + ks * 64 + g * 16);
#pragma unroll
                for (int cf = 0; cf < 4; ++cf) {
                    bf16x8 bv = readKV(Vbase, cf, ks);
                    oacc[cf] = MFMA16(pa, bv, oacc[cf]);
                }
            }
            __builtin_amdgcn_s_setprio(0);
            if (t + 1 < n_act) {
                asm volatile("s_waitcnt vmcnt(4)\n\ts_barrier" ::: "memory");
                __builtin_amdgcn_sched_barrier(0);
            }
        }
    }

#pragma unroll
    for (int cf = 0; cf < 4; ++cf)
#pragma unroll
        for (int r = 0; r < 4; ++r) {
            int t = t0 + g * 4 + r;
            o_out[((size_t)(b * TT + t)) * DD + h * HS + cf * 16 + r15] = (bf16_t)oacc[cf][r];
        }
}

// ---------------- launch ----------------
extern "C" void kernel_launch(void* const* d_in, const int* in_sizes, int n_in, void* d_out, int out_size,
                              void* d_ws, size_t ws_size, hipStream_t stream) {
    const float* x = (const float*)d_in[0];
    const float* Wq = (const float*)d_in[1];
    const float* Wk = (const float*)d_in[2];
    const float* Wv = (const float*)d_in[3];
    const float* Wp = (const float*)d_in[4];
    const float* bp = (const float*)d_in[5];
    const float* W1 = (const float*)d_in[6];
    const float* b1 = (const float*)d_in[7];
    const float* W2 = (const float*)d_in[8];
    const float* b2 = (const float*)d_in[9];
    const float* g1 = (const float*)d_in[10];
    const float* be1 = (const float*)d_in[11];
    const float* g2 = (const float*)d_in[12];
    const float* be2 = (const float*)d_in[13];

    float* out_x = (float*)d_out;
    float* out_attn = out_x + (size_t)BT * DD;

    char* ws = (char*)d_ws;
    bf16_t* hn = (bf16_t*)(ws);                    // 8MB [8192][512]; reused as h2
    bf16_t* qkv = (bf16_t*)(ws + (8ull << 20));    // 24MB: q,k [bh][t][hs]; vT [bh][hs][t]
    bf16_t* ao = (bf16_t*)(ws + (32ull << 20));    // 8MB attn output, [b][t][h*64+hs]
    bf16_t* ff1 = (bf16_t*)(ws + (8ull << 20));    // 32MB, overlaps qkv+ao (both dead by then)
    float* x1 = (float*)(ws + (40ull << 20));      // 16MB fp32
    bf16_t* Wqkv = (bf16_t*)(ws + (56ull << 20));  // 1.5MB
    bf16_t* Wpt = (bf16_t*)(ws + (58ull << 20));   // 0.5MB
    bf16_t* W1t = (bf16_t*)(ws + (59ull << 20));   // 2MB
    bf16_t* W2t = (bf16_t*)(ws + (61ull << 20));   // 2MB
    bf16_t* qq = qkv;
    bf16_t* kk = qkv + 4194304;
    bf16_t* vT = qkv + 8388608;

    pack_fused<<<3072, 256, 0, stream>>>(Wq, Wk, Wv, Wp, W1, W2, Wqkv, Wpt, W1t, W2t);

    ln_kernel<<<BT / 4, 256, 0, stream>>>(x, g1, be1, hn);
    // Fill blocks for attn_out's zero region ride along with ALL four GEMMs (zero region is
    // constant & address-disjoint from attn's active writes, so pre-attn filling is safe):
    // QKV: units [0,288)  proj: [288,416)  FFN1: [416,800)  FFN2: [800,1024)
    gemm_bt<0, 128, 32><<<dim3(88, 12), 256, 0, stream>>>(hn, Wqkv, 1536, 512, nullptr, nullptr, qkv,
                                                          out_attn, 0);
    attn_kernel<<<512, 512, 0, stream>>>(qq, kk, vT, out_attn, ao);
    gemm_bt<1, 64, 64><<<dim3(80, 8), 256, 0, stream>>>(ao, Wpt, 512, 512, bp, x, x1, out_attn, 288);
    ln_kernel<<<BT / 4, 256, 0, stream>>>(x1, g2, be2, hn);
    gemm_bt<2, 128, 32><<<dim3(88, 16), 256, 0, stream>>>(hn, W1t, 2048, 512, b1, nullptr, ff1,
                                                          out_attn, 416);
    gemm_bt<1, 64, 64><<<dim3(92, 8), 256, 0, stream>>>(ff1, W2t, 512, 2048, b2, x1, out_x,
                                                        out_attn, 800);
}